// Round 7
// baseline (392.099 us; speedup 1.0000x reference)
//
#include <hip/hip_runtime.h>

#define B_ 8
#define C_ 256
#define HH 128
#define WW 128
#define HEADS_ 8
#define SCALE 0.17677669529663687f   // 32^-0.5

typedef short v8s __attribute__((ext_vector_type(8)));
typedef float f32x4 __attribute__((ext_vector_type(4)));

__device__ __forceinline__ unsigned short f2bf(float f){
  unsigned int u = __float_as_uint(f);
  u += 0x7FFFu + ((u>>16)&1u);
  return (unsigned short)(u>>16);
}
__device__ __forceinline__ float bf2f(unsigned short s){ return __uint_as_float(((unsigned int)s)<<16); }
__device__ __forceinline__ f32x4 mfma16(v8s a, v8s b, f32x4 c){
  return __builtin_amdgcn_mfma_f32_16x16x32_bf16(a,b,c,0,0,0);
}
__device__ __forceinline__ int xs_idx(int s,int c){ return s*256 + ((((c>>3)^(s&31))&31)<<3) + (c&7); }
__device__ __forceinline__ int wl_idx(int dm,int c){ return dm*256 + ((((c>>3)^(dm&31))&31)<<3) + (c&7); }
__device__ __forceinline__ void gload_lds16(const void* g, void* l){
  __builtin_amdgcn_global_load_lds((const __attribute__((address_space(1))) unsigned int*)g,
                                   (__attribute__((address_space(3))) unsigned int*)l, 16, 0, 0);
}

// ws layout (bytes):
//   [0, 393216)            wsW : 8 heads x (96x256) bf16 pre-swizzled
//   [393216, 524288)       wsWo: 8 oc x (32x256) bf16 pre-swizzled
//   [524288, +3*67108864)  Qw, Kw, Vw : [b][head][16384 pos][32 d] bf16
//   [201850880, +67108864) Ah  : [b][16384 pos][256 c] bf16, chunk-swizzled (^pos&31)
#define WS_OFF_AH 201850880ULL

__global__ __launch_bounds__(512,4)
void prep_w_kernel(const float* __restrict__ Wq, const float* __restrict__ Wk,
                   const float* __restrict__ Wv, const float* __restrict__ Wo,
                   unsigned short* __restrict__ wsW, unsigned short* __restrict__ wsWo){
  const int bid = blockIdx.x, t = threadIdx.x;
  if (bid < 96){
    int h = bid/12, seg = bid%12;
    int dm = seg*8 + (t>>6), c = (t&63)*4;
    const float* Wm = dm<32 ? Wq : (dm<64 ? Wk : Wv);
    const float4 w4 = *(const float4*)&Wm[(h*32 + (dm&31))*C_ + c];
    ushort4 pk = { f2bf(w4.x), f2bf(w4.y), f2bf(w4.z), f2bf(w4.w) };
    *(ushort4*)(wsW + h*24576 + wl_idx(dm, c)) = pk;
  } else {
    int q = bid - 96;
    int oc = q>>2, seg = q&3;
    int o = seg*8 + (t>>6), c = (t&63)*4;
    const float4 w4 = *(const float4*)&Wo[(oc*32+o)*C_ + c];
    ushort4 pk = { f2bf(w4.x), f2bf(w4.y), f2bf(w4.z), f2bf(w4.w) };
    *(ushort4*)(wsWo + oc*8192 + wl_idx(o, c)) = pk;
  }
}

// ---- projh2: projection + horizontal attention, 2 blocks/CU (78.7KB LDS) ----
// Phase 0: stage x tile swizzled in [0,64K), extract per-wave A-frags to regs,
// then region becomes wl(48K)+ql(10K)+kl(10K). Per head: proj MFMA -> repack
// (ql/kl/Vt + Vw short-stores from acc) -> Qw/Kw stores + swapped-QK^T attention
// (R5-verified code) -> Ah. ob (f32[128][36]) aliases ql/kl after barrier D.
__global__ __launch_bounds__(512,4)
void projh2_kernel(const float* __restrict__ x,
                   const float* __restrict__ bq, const float* __restrict__ bk,
                   const float* __restrict__ bv,
                   const unsigned short* __restrict__ wsW,
                   unsigned short* __restrict__ Qw, unsigned short* __restrict__ Kw,
                   unsigned short* __restrict__ Vw, unsigned short* __restrict__ Ah){
  __shared__ __align__(16) char smem[78720];
  unsigned short* xs = (unsigned short*)smem;            // phase 0 only [0,64K)
  unsigned short* wl = (unsigned short*)smem;            // [96][256] swz (48K)
  unsigned short* ql = (unsigned short*)(smem + 49152);  // [128][40] (10240)
  unsigned short* kl = (unsigned short*)(smem + 59392);  // [128][40] (10240)
  float*          ob = (float*)(smem + 49152);           // [128][36] f32, alias post-D
  unsigned short* Vt = (unsigned short*)(smem + 69632);  // [32][136] (8704)
  float* biasl       = (float*)(smem + 78336);           // [96]

  const int tid = threadIdx.x;
  const int b = blockIdx.x >> 7, y = blockIdx.x & 127;
  const size_t pos0 = (size_t)y * 128;

  {  // stage x tile -> xs (bf16 swizzled [pos][c])
    const int cq = (tid>>5)*2, pl = (tid&31)*4;
    #pragma unroll
    for (int j=0;j<8;++j){
      int c0 = j*32 + cq;
      const float4 a0 = *(const float4*)&x[((size_t)(b*C_ + c0  ))*16384 + pos0 + pl];
      const float4 a1 = *(const float4*)&x[((size_t)(b*C_ + c0+1))*16384 + pos0 + pl];
      unsigned int p0 = (unsigned)f2bf(a0.x) | ((unsigned)f2bf(a1.x)<<16);
      unsigned int p1 = (unsigned)f2bf(a0.y) | ((unsigned)f2bf(a1.y)<<16);
      unsigned int p2 = (unsigned)f2bf(a0.z) | ((unsigned)f2bf(a1.z)<<16);
      unsigned int p3 = (unsigned)f2bf(a0.w) | ((unsigned)f2bf(a1.w)<<16);
      *(unsigned int*)&xs[xs_idx(pl+0, c0)] = p0;
      *(unsigned int*)&xs[xs_idx(pl+1, c0)] = p1;
      *(unsigned int*)&xs[xs_idx(pl+2, c0)] = p2;
      *(unsigned int*)&xs[xs_idx(pl+3, c0)] = p3;
    }
  }
  __syncthreads();                     // xs visible

  const int lane = tid&63, wv = tid>>6, lr = lane&15, lk = lane>>4;
  v8s areg[8];
  #pragma unroll
  for (int ks=0;ks<8;++ks) areg[ks] = *(const v8s*)(xs + xs_idx(wv*16+lr, ks*32+lk*8));
  __syncthreads();                     // xs consumed; region becomes wl/ql/kl

  {  // issue wl(head 0)
    const char* wb = (const char*)wsW;
    for (int rIt=0;rIt<6;++rIt)
      gload_lds16(wb + (rIt*512+tid)*16, (char*)wl + (rIt*512+tid)*16);
  }

  const f32x4 zero4 = {0.f,0.f,0.f,0.f};
  for (int h=0; h<HEADS_; ++h){
    const size_t tbh = (size_t)(b*HEADS_+h)*16384*32;
    __syncthreads();                   // A: wl(h) ready (vmcnt drained); ob free
    if (tid<96){
      int mat = tid>>5;
      const float* bm = mat==0?bq:(mat==1?bk:bv);
      biasl[tid] = bm[h*32 + (tid&31)];
    }
    // ---- projection MFMA ----
    f32x4 acc[6];
    #pragma unroll
    for (int n=0;n<6;++n) acc[n]=zero4;
    #pragma unroll
    for (int ks=0;ks<8;++ks){
      int c0 = ks*32 + lk*8;
      #pragma unroll
      for (int n=0;n<6;++n){
        v8s bb = *(const v8s*)(wl + wl_idx(n*16+lr, c0));
        acc[n] = mfma16(areg[ks], bb, acc[n]);
      }
    }
    __syncthreads();                   // B: wl reads done; biasl visible
    if (h < HEADS_-1){                 // prefetch wl(h+1) -- hides under attention
      const char* wb = (const char*)wsW + (h+1)*49152;
      for (int rIt=0;rIt<6;++rIt)
        gload_lds16(wb + (rIt*512+tid)*16, (char*)wl + (rIt*512+tid)*16);
    }
    // ---- repack: ql/kl [pos][40], Vt[d][slot] + direct Vw short-stores ----
    #pragma unroll
    for (int n=0;n<6;++n){
      int dm = n*16+lr;
      float bia = biasl[dm];
      #pragma unroll
      for (int rr=0;rr<4;++rr){
        int pos = wv*16 + lk*4 + rr;
        float val = acc[n][rr] + bia;
        if (n<2){
          ql[pos*40 + n*16 + lr] = f2bf(val * SCALE);
        } else if (n<4){
          kl[pos*40 + (n-2)*16 + lr] = f2bf(val);
        } else {
          unsigned short bv16 = f2bf(val);
          int slot = (pos & ~31) | (((pos>>2)&3)<<3) | (((pos>>4)&1)<<2) | (pos&3);
          Vt[((n-4)*16+lr)*136 + slot] = bv16;
          Vw[tbh + (pos0 + pos)*32 + (n-4)*16 + lr] = bv16;
        }
      }
    }
    __syncthreads();                   // C: ql/kl/Vt visible
    {  // Qw/Kw stores for the vertical pass
      int p = tid>>2, ch = tid&3;
      v8s qd = *(const v8s*)&ql[p*40 + ch*8];
      v8s kd = *(const v8s*)&kl[p*40 + ch*8];
      size_t og = tbh + (pos0 + p)*32 + ch*8;
      *(v8s*)(Qw + og) = qd;
      *(v8s*)(Kw + og) = kd;
    }
    // ---- horizontal attention (row y), swapped QK^T (verified R5 code) ----
    v8s qa = *(const v8s*)&ql[(wv*16+lr)*40 + lk*8];
    f32x4 sc[8];
    #pragma unroll
    for (int kt=0;kt<8;++kt){
      v8s kb = *(const v8s*)&kl[(kt*16+lr)*40 + lk*8];
      sc[kt] = mfma16(kb, qa, zero4);
    }
    float mx = sc[0][0];
    #pragma unroll
    for (int kt=0;kt<8;++kt){
      #pragma unroll
      for (int rr=0;rr<4;++rr) mx = fmaxf(mx, sc[kt][rr]);
    }
    mx = fmaxf(mx, __shfl_xor(mx, 16));
    mx = fmaxf(mx, __shfl_xor(mx, 32));
    float sm = 0.f;
    #pragma unroll
    for (int kt=0;kt<8;++kt){
      #pragma unroll
      for (int rr=0;rr<4;++rr){ float p = __expf(sc[kt][rr]-mx); sc[kt][rr]=p; sm += p; }
    }
    sm += __shfl_xor(sm, 16);
    sm += __shfl_xor(sm, 32);
    const float rn = 1.f/sm;
    unsigned int pk[16];
    #pragma unroll
    for (int kt=0;kt<8;++kt){
      pk[kt*2  ] = (unsigned)f2bf(sc[kt][0]*rn) | ((unsigned)f2bf(sc[kt][1]*rn)<<16);
      pk[kt*2+1] = (unsigned)f2bf(sc[kt][2]*rn) | ((unsigned)f2bf(sc[kt][3]*rn)<<16);
    }
    f32x4 o0 = zero4, o1 = zero4;
    #pragma unroll
    for (int ks=0;ks<4;++ks){
      union { unsigned int u[4]; v8s v; } pa;
      pa.u[0]=pk[4*ks]; pa.u[1]=pk[4*ks+1]; pa.u[2]=pk[4*ks+2]; pa.u[3]=pk[4*ks+3];
      v8s v0 = *(const v8s*)&Vt[(     lr)*136 + ks*32 + lk*8];
      v8s v1 = *(const v8s*)&Vt[(16 + lr)*136 + ks*32 + lk*8];
      o0 = mfma16(pa.v, v0, o0);
      o1 = mfma16(pa.v, v1, o1);
    }
    __syncthreads();                   // D: ql/kl/Vt reads done -> ob alias safe
    #pragma unroll
    for (int rr=0;rr<4;++rr){
      int s = wv*16 + lk*4 + rr;
      ob[s*36 + lr     ] = o0[rr];
      ob[s*36 + 16 + lr] = o1[rr];
    }
    {  // Ah write (wave-private ob rows)
      int row = wv*16 + (lane>>2), jj = lane&3;
      f32x4 fa = *(const f32x4*)&ob[row*36 + jj*8];
      f32x4 fb = *(const f32x4*)&ob[row*36 + jj*8 + 4];
      int pos = y*128 + row;
      size_t ga = ((size_t)b*16384 + pos)*256 + (size_t)(((h*4+jj)^(pos&31))<<3);
      v8s outv;
      #pragma unroll
      for (int j=0;j<4;++j){
        outv[j]   = (short)f2bf(fa[j]);
        outv[4+j] = (short)f2bf(fb[j]);
      }
      *(v8s*)(Ah + ga) = outv;
    }
  }
}

// ---- vertical attention (R4-proven) ----
template<int VERT>
__global__ __launch_bounds__(512,6)
void attn2_kernel(const unsigned short* __restrict__ Qw, const unsigned short* __restrict__ Kw,
                  const unsigned short* __restrict__ Vw, unsigned short* __restrict__ Ah){
  __shared__ __align__(16) char smem[37376];
  unsigned short* kl = (unsigned short*)smem;            // [128 key][40 d]
  unsigned short* Vt = (unsigned short*)(smem + 10240);  // [32 d][136 slot]
  float*          ob = (float*)(smem + 18944);           // [128 s][36 d]

  const int tid = threadIdx.x;
  int b, head, fix;
  if (VERT){ int xcd = blockIdx.x&7, rest = blockIdx.x>>3;
             fix = xcd*16 + (rest&15); head = (rest>>4)&7; b = rest>>7; }
  else     { head = blockIdx.x&7; fix = (blockIdx.x>>3)&127; b = blockIdx.x>>10; }
  const size_t tb = (size_t)(b*HEADS_+head)*16384*32;
  const int lane = tid&63, wvq = tid>>6, lr = lane&15, lk = lane>>4;
  const f32x4 zero4 = {0.f,0.f,0.f,0.f};

  {
    int pl = tid>>2, ch = tid&3;
    size_t g = tb + (VERT ? ((size_t)pl*128 + fix) : ((size_t)fix*128 + pl))*32 + ch*8;
    v8s kv = *(const v8s*)(Kw + g);
    v8s vv = *(const v8s*)(Vw + g);
    *(v8s*)&kl[pl*40 + ch*8] = kv;
    int slot = (pl & ~31) | (((pl>>2)&3)<<3) | (((pl>>4)&1)<<2) | (pl&3);
    #pragma unroll
    for (int j=0;j<8;++j) Vt[(ch*8+j)*136 + slot] = (unsigned short)vv[j];
  }
  const int posq = VERT ? (wvq*16+lr)*128 + fix : fix*128 + (wvq*16+lr);
  v8s qa = *(const v8s*)(Qw + tb + (size_t)posq*32 + lk*8);
  __syncthreads();

  f32x4 sc[8];
  #pragma unroll
  for (int kt=0;kt<8;++kt){
    v8s kb = *(const v8s*)&kl[(kt*16+lr)*40 + lk*8];
    sc[kt] = mfma16(kb, qa, zero4);
  }
  float mx = sc[0][0];
  #pragma unroll
  for (int kt=0;kt<8;++kt){
    #pragma unroll
    for (int rr=0;rr<4;++rr) mx = fmaxf(mx, sc[kt][rr]);
  }
  mx = fmaxf(mx, __shfl_xor(mx, 16));
  mx = fmaxf(mx, __shfl_xor(mx, 32));
  float sm = 0.f;
  #pragma unroll
  for (int kt=0;kt<8;++kt){
    #pragma unroll
    for (int rr=0;rr<4;++rr){ float p = __expf(sc[kt][rr]-mx); sc[kt][rr]=p; sm += p; }
  }
  sm += __shfl_xor(sm, 16);
  sm += __shfl_xor(sm, 32);
  const float rn = 1.f/sm;
  unsigned int pk[16];
  #pragma unroll
  for (int kt=0;kt<8;++kt){
    pk[kt*2  ] = (unsigned)f2bf(sc[kt][0]*rn) | ((unsigned)f2bf(sc[kt][1]*rn)<<16);
    pk[kt*2+1] = (unsigned)f2bf(sc[kt][2]*rn) | ((unsigned)f2bf(sc[kt][3]*rn)<<16);
  }
  f32x4 o0 = zero4, o1 = zero4;
  #pragma unroll
  for (int ks=0;ks<4;++ks){
    union { unsigned int u[4]; v8s v; } pa;
    pa.u[0]=pk[4*ks]; pa.u[1]=pk[4*ks+1]; pa.u[2]=pk[4*ks+2]; pa.u[3]=pk[4*ks+3];
    v8s v0 = *(const v8s*)&Vt[(     lr)*136 + ks*32 + lk*8];
    v8s v1 = *(const v8s*)&Vt[(16 + lr)*136 + ks*32 + lk*8];
    o0 = mfma16(pa.v, v0, o0);
    o1 = mfma16(pa.v, v1, o1);
  }
  #pragma unroll
  for (int rr=0;rr<4;++rr){
    int s = wvq*16 + lk*4 + rr;
    ob[s*36 + lr     ] = o0[rr];
    ob[s*36 + 16 + lr] = o1[rr];
  }
  {
    int row = wvq*16 + (lane>>2), jj = lane&3;
    f32x4 fa = *(const f32x4*)&ob[row*36 + jj*8];
    f32x4 fb = *(const f32x4*)&ob[row*36 + jj*8 + 4];
    int pos = VERT ? row*128 + fix : fix*128 + row;
    size_t ga = ((size_t)b*16384 + pos)*256 + (size_t)(((head*4+jj)^(pos&31))<<3);
    if (VERT){
      v8s prev = *(const v8s*)(Ah + ga);
      v8s outv;
      #pragma unroll
      for (int j=0;j<4;++j){
        outv[j]   = (short)f2bf(bf2f((unsigned short)prev[j])   + fa[j]);
        outv[4+j] = (short)f2bf(bf2f((unsigned short)prev[4+j]) + fb[j]);
      }
      *(v8s*)(Ah + ga) = outv;
    } else {
      v8s outv;
      #pragma unroll
      for (int j=0;j<4;++j){
        outv[j]   = (short)f2bf(fa[j]);
        outv[4+j] = (short)f2bf(fb[j]);
      }
      *(v8s*)(Ah + ga) = outv;
    }
  }
}

// ---- final: Ah via global_load_lds, GEMM Wo, +bias(direct) +x; 80KB -> 2 blk/CU ----
__global__ __launch_bounds__(512,4)
void final2_kernel(const float* __restrict__ x, const unsigned short* __restrict__ wsWo,
                   const float* __restrict__ bo, const unsigned short* __restrict__ Ah,
                   float* __restrict__ out)
{
  __shared__ __align__(16) char smem[81920];
  unsigned short* asl = (unsigned short*)smem;            // [128 pos][256 c] swz
  unsigned short* wol = (unsigned short*)(smem + 65536);  // [32 o][256 c] swz

  const int tid = threadIdx.x;
  const int b = blockIdx.x >> 7, pt = blockIdx.x & 127;
  {
    const char* ab = (const char*)(Ah + ((size_t)b*16384 + (size_t)pt*128)*256);
    for (int i=0;i<8;++i)
      gload_lds16(ab + (i*512+tid)*16, (char*)asl + (i*512+tid)*16);
  }
  const int lane = tid & 63, wv = tid >> 6;
  const int lr = lane & 15, lk = lane >> 4;
  const f32x4 zero4 = {0.f,0.f,0.f,0.f};

  for (int oc = 0; oc < 8; ++oc){
    {
      const char* wb = (const char*)wsWo + oc*16384;
      for (int rIt=0;rIt<2;++rIt)
        gload_lds16(wb + (rIt*512+tid)*16, (char*)wol + (rIt*512+tid)*16);
    }
    const float b0v = bo[oc*32 + lr], b1v = bo[oc*32 + 16 + lr];
    __syncthreads();

    f32x4 a0 = zero4, a1 = zero4;
    #pragma unroll
    for (int ks = 0; ks < 8; ++ks){
      int c0 = ks*32 + lk*8;
      v8s av = *(const v8s*)(asl + xs_idx(wv*16 + lr, c0));
      v8s b0 = *(const v8s*)(wol + wl_idx(     lr, c0));
      v8s b1 = *(const v8s*)(wol + wl_idx(16 + lr, c0));
      a0 = mfma16(av, b0, a0);
      a1 = mfma16(av, b1, a1);
    }
    {
      int base0 = ((b*C_ + oc*32 + lr)*HH)*WW + pt*128 + wv*16 + lk*4;
      f32x4 xv0 = *(const f32x4*)(x + base0);
      f32x4 xv1 = *(const f32x4*)(x + base0 + 16*HH*WW);
      f32x4 r0 = a0 + xv0 + b0v;
      f32x4 r1 = a1 + xv1 + b1v;
      *(f32x4*)(out + base0) = r0;
      *(f32x4*)(out + base0 + 16*HH*WW) = r1;
    }
    __syncthreads();
  }
}

extern "C" void kernel_launch(void* const* d_in, const int* in_sizes, int n_in,
                              void* d_out, int out_size, void* d_ws, size_t ws_size,
                              hipStream_t stream) {
  const float* x  = (const float*)d_in[0];
  const float* Wq = (const float*)d_in[1];
  const float* bq = (const float*)d_in[2];
  const float* Wk = (const float*)d_in[3];
  const float* bk = (const float*)d_in[4];
  const float* Wv = (const float*)d_in[5];
  const float* bv = (const float*)d_in[6];
  const float* Wo = (const float*)d_in[7];
  const float* bo = (const float*)d_in[8];
  float* out = (float*)d_out;

  unsigned short* wsW  = (unsigned short*)d_ws;
  unsigned short* wsWo = (unsigned short*)((char*)d_ws + 393216);
  unsigned short* Qw   = (unsigned short*)((char*)d_ws + 524288);
  unsigned short* Kw   = Qw + 33554432;
  unsigned short* Vw   = Kw + 33554432;
  unsigned short* Ah   = (unsigned short*)((char*)d_ws + WS_OFF_AH);

  prep_w_kernel<<<dim3(128),  dim3(512), 0, stream>>>(Wq, Wk, Wv, Wo, wsW, wsWo);
  projh2_kernel<<<dim3(1024), dim3(512), 0, stream>>>(x, bq, bk, bv, wsW, Qw, Kw, Vw, Ah);
  attn2_kernel<1><<<dim3(8192), dim3(512), 0, stream>>>(Qw, Kw, Vw, Ah);
  final2_kernel<<<dim3(1024), dim3(512), 0, stream>>>(x, wsWo, bo, Ah, out);
}

// Round 8
// 316.141 us; speedup vs baseline: 1.2403x; 1.2403x over previous
//
#include <hip/hip_runtime.h>

#define B_ 8
#define C_ 256
#define HH 128
#define WW 128
#define HEADS_ 8
#define SCALE 0.17677669529663687f   // 32^-0.5

typedef short v8s __attribute__((ext_vector_type(8)));
typedef float f32x4 __attribute__((ext_vector_type(4)));

__device__ __forceinline__ unsigned short f2bf(float f){
  unsigned int u = __float_as_uint(f);
  u += 0x7FFFu + ((u>>16)&1u);
  return (unsigned short)(u>>16);
}
__device__ __forceinline__ float bf2f(unsigned short s){ return __uint_as_float(((unsigned int)s)<<16); }
__device__ __forceinline__ f32x4 mfma16(v8s a, v8s b, f32x4 c){
  return __builtin_amdgcn_mfma_f32_16x16x32_bf16(a,b,c,0,0,0);
}
__device__ __forceinline__ int xs_idx(int s,int c){ return s*256 + ((((c>>3)^(s&31))&31)<<3) + (c&7); }
__device__ __forceinline__ int wl_idx(int dm,int c){ return dm*256 + ((((c>>3)^(dm&31))&31)<<3) + (c&7); }
__device__ __forceinline__ void gload_lds16(const void* g, void* l){
  __builtin_amdgcn_global_load_lds((const __attribute__((address_space(1))) unsigned int*)g,
                                   (__attribute__((address_space(3))) unsigned int*)l, 16, 0, 0);
}

// ws layout (bytes):
//   [0, 393216)            wsW : 8 heads x (96x256) bf16 pre-swizzled
//   [393216, 524288)       wsWo: 8 oc x (32x256) bf16 pre-swizzled
//   [524288, +3*67108864)  Qw, Kw, Vw : [b][head][16384 pos][32 d] bf16
//   [201850880, +67108864) Ah  : [b][16384 pos][256 c] bf16, chunk-swizzled (^pos&31)
#define WS_OFF_AH 201850880ULL

__global__ __launch_bounds__(512,4)
void prep_w_kernel(const float* __restrict__ Wq, const float* __restrict__ Wk,
                   const float* __restrict__ Wv, const float* __restrict__ Wo,
                   unsigned short* __restrict__ wsW, unsigned short* __restrict__ wsWo){
  const int bid = blockIdx.x, t = threadIdx.x;
  if (bid < 96){
    int h = bid/12, seg = bid%12;
    int dm = seg*8 + (t>>6), c = (t&63)*4;
    const float* Wm = dm<32 ? Wq : (dm<64 ? Wk : Wv);
    const float4 w4 = *(const float4*)&Wm[(h*32 + (dm&31))*C_ + c];
    ushort4 pk = { f2bf(w4.x), f2bf(w4.y), f2bf(w4.z), f2bf(w4.w) };
    *(ushort4*)(wsW + h*24576 + wl_idx(dm, c)) = pk;
  } else {
    int q = bid - 96;
    int oc = q>>2, seg = q&3;
    int o = seg*8 + (t>>6), c = (t&63)*4;
    const float4 w4 = *(const float4*)&Wo[(oc*32+o)*C_ + c];
    ushort4 pk = { f2bf(w4.x), f2bf(w4.y), f2bf(w4.z), f2bf(w4.w) };
    *(ushort4*)(wsWo + oc*8192 + wl_idx(o, c)) = pk;
  }
}

// ---- proj4: m=2 register blocking (halved B-frag LDS reads) + overlapped writeout ----
// Wave w<4: n-tiles 0..2, M-tiles {2w,2w+1}. Wave w>=4: n-tiles 3..5, M-tiles {2(w-4),...}.
// Per head: A-barrier (wl ready, rp(h-1) visible) -> MFMA(h) || writeout(h-1) ->
// B-barrier -> prefetch wl(h+1), repack acc->rp. Epilogue writes rp(7).
__global__ __launch_bounds__(512,4)
void proj4_kernel(const float* __restrict__ x,
                  const float* __restrict__ bq, const float* __restrict__ bk,
                  const float* __restrict__ bv,
                  const unsigned short* __restrict__ wsW,
                  unsigned short* __restrict__ Qw, unsigned short* __restrict__ Kw,
                  unsigned short* __restrict__ Vw){
  __shared__ __align__(16) char smem[76800];
  unsigned short* xs = (unsigned short*)smem;            // phase 0 only (64K)
  unsigned short* wl = (unsigned short*)smem;            // [96][256] swz (48K)
  unsigned short* rp = (unsigned short*)(smem + 49152);  // [128][104] (26.6K)

  const int tid = threadIdx.x;
  const int b = blockIdx.x >> 7, pt = blockIdx.x & 127;
  const size_t pos0 = (size_t)pt * 128;

  {  // stage x tile -> xs (bf16 swizzled [pos][c])
    const int cq = (tid>>5)*2, pl = (tid&31)*4;
    #pragma unroll
    for (int j=0;j<8;++j){
      int c0 = j*32 + cq;
      const float4 a0 = *(const float4*)&x[((size_t)(b*C_ + c0  ))*16384 + pos0 + pl];
      const float4 a1 = *(const float4*)&x[((size_t)(b*C_ + c0+1))*16384 + pos0 + pl];
      unsigned int p0 = (unsigned)f2bf(a0.x) | ((unsigned)f2bf(a1.x)<<16);
      unsigned int p1 = (unsigned)f2bf(a0.y) | ((unsigned)f2bf(a1.y)<<16);
      unsigned int p2 = (unsigned)f2bf(a0.z) | ((unsigned)f2bf(a1.z)<<16);
      unsigned int p3 = (unsigned)f2bf(a0.w) | ((unsigned)f2bf(a1.w)<<16);
      *(unsigned int*)&xs[xs_idx(pl+0, c0)] = p0;
      *(unsigned int*)&xs[xs_idx(pl+1, c0)] = p1;
      *(unsigned int*)&xs[xs_idx(pl+2, c0)] = p2;
      *(unsigned int*)&xs[xs_idx(pl+3, c0)] = p3;
    }
  }
  __syncthreads();                     // xs visible

  const int lane = tid&63, wv = tid>>6, lr = lane&15, lk = lane>>4;
  const int mbase = (wv&3)*2;          // this wave's two M-tiles
  const int nb    = (wv>>2)*3;         // this wave's n-tile base (0 or 3)
  v8s areg0[8], areg1[8];
  #pragma unroll
  for (int ks=0;ks<8;++ks){
    areg0[ks] = *(const v8s*)(xs + xs_idx((mbase  )*16+lr, ks*32+lk*8));
    areg1[ks] = *(const v8s*)(xs + xs_idx((mbase+1)*16+lr, ks*32+lk*8));
  }
  __syncthreads();                     // xs consumed; region becomes wl

  {  // issue wl(head 0)
    const char* wb = (const char*)wsW;
    for (int rIt=0;rIt<6;++rIt)
      gload_lds16(wb + (rIt*512+tid)*16, (char*)wl + (rIt*512+tid)*16);
  }

  const f32x4 zero4 = {0.f,0.f,0.f,0.f};
  const int wp = tid>>2, wch = tid&3;  // writeout mapping (block-wide)

  for (int h=0; h<HEADS_; ++h){
    __syncthreads();                   // A: wl(h) drained; rp(h-1) visible
    // bias for this wave's 3 n-tiles (direct global, coalesced 16-lane runs)
    float bias_[3];
    #pragma unroll
    for (int ni=0;ni<3;++ni){
      int n = nb + ni;
      const float* bm = (n>>1)==0 ? bq : ((n>>1)==1 ? bk : bv);
      bias_[ni] = bm[h*32 + (n&1)*16 + lr];
    }
    // ---- writeout(h-1) issues here; overlaps MFMA below ----
    if (h > 0){
      v8s qd = *(const v8s*)&rp[wp*104 +      wch*8];
      v8s kd = *(const v8s*)&rp[wp*104 + 32 + wch*8];
      v8s vd = *(const v8s*)&rp[wp*104 + 64 + wch*8];
      size_t og = ((size_t)(b*HEADS_+(h-1))*16384 + pos0 + wp)*32 + wch*8;
      *(v8s*)(Qw + og) = qd;
      *(v8s*)(Kw + og) = kd;
      *(v8s*)(Vw + og) = vd;
    }
    // ---- projection MFMA: 3 n-tiles x 2 M-tiles x 8 ks ----
    f32x4 acc[3][2];
    #pragma unroll
    for (int ni=0;ni<3;++ni){ acc[ni][0]=zero4; acc[ni][1]=zero4; }
    #pragma unroll
    for (int ks=0;ks<8;++ks){
      int c0 = ks*32 + lk*8;
      #pragma unroll
      for (int ni=0;ni<3;++ni){
        v8s bb = *(const v8s*)(wl + wl_idx((nb+ni)*16+lr, c0));
        acc[ni][0] = mfma16(areg0[ks], bb, acc[ni][0]);
        acc[ni][1] = mfma16(areg1[ks], bb, acc[ni][1]);
      }
    }
    __syncthreads();                   // B: wl reads + rp reads done
    if (h < HEADS_-1){                 // prefetch wl(h+1)
      const char* wb = (const char*)wsW + (h+1)*49152;
      for (int rIt=0;rIt<6;++rIt)
        gload_lds16(wb + (rIt*512+tid)*16, (char*)wl + (rIt*512+tid)*16);
    }
    // ---- repack acc(h) -> rp (+bias, q scaled) ----
    #pragma unroll
    for (int ni=0;ni<3;++ni){
      int n = nb + ni;
      int dm = n*16 + lr;
      float bia = bias_[ni];
      #pragma unroll
      for (int mi=0;mi<2;++mi){
        #pragma unroll
        for (int rr=0;rr<4;++rr){
          int pos = (mbase+mi)*16 + lk*4 + rr;
          float val = acc[ni][mi][rr] + bia;
          if (n<2) val *= SCALE;
          rp[pos*104 + dm] = f2bf(val);
        }
      }
    }
  }
  __syncthreads();                     // rp(7) visible
  {
    v8s qd = *(const v8s*)&rp[wp*104 +      wch*8];
    v8s kd = *(const v8s*)&rp[wp*104 + 32 + wch*8];
    v8s vd = *(const v8s*)&rp[wp*104 + 64 + wch*8];
    size_t og = ((size_t)(b*HEADS_+7)*16384 + pos0 + wp)*32 + wch*8;
    *(v8s*)(Qw + og) = qd;
    *(v8s*)(Kw + og) = kd;
    *(v8s*)(Vw + og) = vd;
  }
}

// ---- attention (R4-proven): swapped QK^T, in-register PV, bf16 Ah output ----
template<int VERT>
__global__ __launch_bounds__(512,6)
void attn2_kernel(const unsigned short* __restrict__ Qw, const unsigned short* __restrict__ Kw,
                  const unsigned short* __restrict__ Vw, unsigned short* __restrict__ Ah){
  __shared__ __align__(16) char smem[37376];
  unsigned short* kl = (unsigned short*)smem;            // [128 key][40 d]
  unsigned short* Vt = (unsigned short*)(smem + 10240);  // [32 d][136 slot]
  float*          ob = (float*)(smem + 18944);           // [128 s][36 d]

  const int tid = threadIdx.x;
  int b, head, fix;
  if (VERT){ int xcd = blockIdx.x&7, rest = blockIdx.x>>3;
             fix = xcd*16 + (rest&15); head = (rest>>4)&7; b = rest>>7; }
  else     { head = blockIdx.x&7; fix = (blockIdx.x>>3)&127; b = blockIdx.x>>10; }
  const size_t tb = (size_t)(b*HEADS_+head)*16384*32;
  const int lane = tid&63, wvq = tid>>6, lr = lane&15, lk = lane>>4;
  const f32x4 zero4 = {0.f,0.f,0.f,0.f};

  {
    int pl = tid>>2, ch = tid&3;
    size_t g = tb + (VERT ? ((size_t)pl*128 + fix) : ((size_t)fix*128 + pl))*32 + ch*8;
    v8s kv = *(const v8s*)(Kw + g);
    v8s vv = *(const v8s*)(Vw + g);
    *(v8s*)&kl[pl*40 + ch*8] = kv;
    int slot = (pl & ~31) | (((pl>>2)&3)<<3) | (((pl>>4)&1)<<2) | (pl&3);
    #pragma unroll
    for (int j=0;j<8;++j) Vt[(ch*8+j)*136 + slot] = (unsigned short)vv[j];
  }
  const int posq = VERT ? (wvq*16+lr)*128 + fix : fix*128 + (wvq*16+lr);
  v8s qa = *(const v8s*)(Qw + tb + (size_t)posq*32 + lk*8);
  __syncthreads();

  f32x4 sc[8];
  #pragma unroll
  for (int kt=0;kt<8;++kt){
    v8s kb = *(const v8s*)&kl[(kt*16+lr)*40 + lk*8];
    sc[kt] = mfma16(kb, qa, zero4);
  }
  float mx = sc[0][0];
  #pragma unroll
  for (int kt=0;kt<8;++kt){
    #pragma unroll
    for (int rr=0;rr<4;++rr) mx = fmaxf(mx, sc[kt][rr]);
  }
  mx = fmaxf(mx, __shfl_xor(mx, 16));
  mx = fmaxf(mx, __shfl_xor(mx, 32));
  float sm = 0.f;
  #pragma unroll
  for (int kt=0;kt<8;++kt){
    #pragma unroll
    for (int rr=0;rr<4;++rr){ float p = __expf(sc[kt][rr]-mx); sc[kt][rr]=p; sm += p; }
  }
  sm += __shfl_xor(sm, 16);
  sm += __shfl_xor(sm, 32);
  const float rn = 1.f/sm;
  unsigned int pk[16];
  #pragma unroll
  for (int kt=0;kt<8;++kt){
    pk[kt*2  ] = (unsigned)f2bf(sc[kt][0]*rn) | ((unsigned)f2bf(sc[kt][1]*rn)<<16);
    pk[kt*2+1] = (unsigned)f2bf(sc[kt][2]*rn) | ((unsigned)f2bf(sc[kt][3]*rn)<<16);
  }
  f32x4 o0 = zero4, o1 = zero4;
  #pragma unroll
  for (int ks=0;ks<4;++ks){
    union { unsigned int u[4]; v8s v; } pa;
    pa.u[0]=pk[4*ks]; pa.u[1]=pk[4*ks+1]; pa.u[2]=pk[4*ks+2]; pa.u[3]=pk[4*ks+3];
    v8s v0 = *(const v8s*)&Vt[(     lr)*136 + ks*32 + lk*8];
    v8s v1 = *(const v8s*)&Vt[(16 + lr)*136 + ks*32 + lk*8];
    o0 = mfma16(pa.v, v0, o0);
    o1 = mfma16(pa.v, v1, o1);
  }
  #pragma unroll
  for (int rr=0;rr<4;++rr){
    int s = wvq*16 + lk*4 + rr;
    ob[s*36 + lr     ] = o0[rr];
    ob[s*36 + 16 + lr] = o1[rr];
  }
  {
    int row = wvq*16 + (lane>>2), jj = lane&3;
    f32x4 fa = *(const f32x4*)&ob[row*36 + jj*8];
    f32x4 fb = *(const f32x4*)&ob[row*36 + jj*8 + 4];
    int pos = VERT ? row*128 + fix : fix*128 + row;
    size_t ga = ((size_t)b*16384 + pos)*256 + (size_t)(((head*4+jj)^(pos&31))<<3);
    if (VERT){
      v8s prev = *(const v8s*)(Ah + ga);
      v8s outv;
      #pragma unroll
      for (int j=0;j<4;++j){
        outv[j]   = (short)f2bf(bf2f((unsigned short)prev[j])   + fa[j]);
        outv[4+j] = (short)f2bf(bf2f((unsigned short)prev[4+j]) + fb[j]);
      }
      *(v8s*)(Ah + ga) = outv;
    } else {
      v8s outv;
      #pragma unroll
      for (int j=0;j<4;++j){
        outv[j]   = (short)f2bf(fa[j]);
        outv[4+j] = (short)f2bf(fb[j]);
      }
      *(v8s*)(Ah + ga) = outv;
    }
  }
}

// ---- final: Ah via global_load_lds, GEMM Wo, +bias(direct) +x; 80KB -> 2 blk/CU ----
__global__ __launch_bounds__(512,4)
void final2_kernel(const float* __restrict__ x, const unsigned short* __restrict__ wsWo,
                   const float* __restrict__ bo, const unsigned short* __restrict__ Ah,
                   float* __restrict__ out)
{
  __shared__ __align__(16) char smem[81920];
  unsigned short* asl = (unsigned short*)smem;            // [128 pos][256 c] swz
  unsigned short* wol = (unsigned short*)(smem + 65536);  // [32 o][256 c] swz

  const int tid = threadIdx.x;
  const int b = blockIdx.x >> 7, pt = blockIdx.x & 127;
  {
    const char* ab = (const char*)(Ah + ((size_t)b*16384 + (size_t)pt*128)*256);
    for (int i=0;i<8;++i)
      gload_lds16(ab + (i*512+tid)*16, (char*)asl + (i*512+tid)*16);
  }
  const int lane = tid & 63, wv = tid >> 6;
  const int lr = lane & 15, lk = lane >> 4;
  const f32x4 zero4 = {0.f,0.f,0.f,0.f};

  for (int oc = 0; oc < 8; ++oc){
    {
      const char* wb = (const char*)wsWo + oc*16384;
      for (int rIt=0;rIt<2;++rIt)
        gload_lds16(wb + (rIt*512+tid)*16, (char*)wol + (rIt*512+tid)*16);
    }
    const float b0v = bo[oc*32 + lr], b1v = bo[oc*32 + 16 + lr];
    __syncthreads();

    f32x4 a0 = zero4, a1 = zero4;
    #pragma unroll
    for (int ks = 0; ks < 8; ++ks){
      int c0 = ks*32 + lk*8;
      v8s av = *(const v8s*)(asl + xs_idx(wv*16 + lr, c0));
      v8s b0 = *(const v8s*)(wol + wl_idx(     lr, c0));
      v8s b1 = *(const v8s*)(wol + wl_idx(16 + lr, c0));
      a0 = mfma16(av, b0, a0);
      a1 = mfma16(av, b1, a1);
    }
    {
      int base0 = ((b*C_ + oc*32 + lr)*HH)*WW + pt*128 + wv*16 + lk*4;
      f32x4 xv0 = *(const f32x4*)(x + base0);
      f32x4 xv1 = *(const f32x4*)(x + base0 + 16*HH*WW);
      f32x4 r0 = a0 + xv0 + b0v;
      f32x4 r1 = a1 + xv1 + b1v;
      *(f32x4*)(out + base0) = r0;
      *(f32x4*)(out + base0 + 16*HH*WW) = r1;
    }
    __syncthreads();
  }
}

extern "C" void kernel_launch(void* const* d_in, const int* in_sizes, int n_in,
                              void* d_out, int out_size, void* d_ws, size_t ws_size,
                              hipStream_t stream) {
  const float* x  = (const float*)d_in[0];
  const float* Wq = (const float*)d_in[1];
  const float* bq = (const float*)d_in[2];
  const float* Wk = (const float*)d_in[3];
  const float* bk = (const float*)d_in[4];
  const float* Wv = (const float*)d_in[5];
  const float* bv = (const float*)d_in[6];
  const float* Wo = (const float*)d_in[7];
  const float* bo = (const float*)d_in[8];
  float* out = (float*)d_out;

  unsigned short* wsW  = (unsigned short*)d_ws;
  unsigned short* wsWo = (unsigned short*)((char*)d_ws + 393216);
  unsigned short* Qw   = (unsigned short*)((char*)d_ws + 524288);
  unsigned short* Kw   = Qw + 33554432;
  unsigned short* Vw   = Kw + 33554432;
  unsigned short* Ah   = (unsigned short*)((char*)d_ws + WS_OFF_AH);

  prep_w_kernel<<<dim3(128),  dim3(512), 0, stream>>>(Wq, Wk, Wv, Wo, wsW, wsWo);
  proj4_kernel <<<dim3(1024), dim3(512), 0, stream>>>(x, bq, bk, bv, wsW, Qw, Kw, Vw);
  attn2_kernel<0><<<dim3(8192), dim3(512), 0, stream>>>(Qw, Kw, Vw, Ah);
  attn2_kernel<1><<<dim3(8192), dim3(512), 0, stream>>>(Qw, Kw, Vw, Ah);
  final2_kernel<<<dim3(1024), dim3(512), 0, stream>>>(x, wsWo, bo, Ah, out);
}

// Round 9
// 290.310 us; speedup vs baseline: 1.3506x; 1.0890x over previous
//
#include <hip/hip_runtime.h>

#define B_ 8
#define C_ 256
#define HH 128
#define WW 128
#define HEADS_ 8
#define SCALE 0.17677669529663687f   // 32^-0.5

typedef short v8s __attribute__((ext_vector_type(8)));
typedef float f32x4 __attribute__((ext_vector_type(4)));

__device__ __forceinline__ unsigned short f2bf(float f){
  unsigned int u = __float_as_uint(f);
  u += 0x7FFFu + ((u>>16)&1u);
  return (unsigned short)(u>>16);
}
__device__ __forceinline__ float bf2f(unsigned short s){ return __uint_as_float(((unsigned int)s)<<16); }
__device__ __forceinline__ f32x4 mfma16(v8s a, v8s b, f32x4 c){
  return __builtin_amdgcn_mfma_f32_16x16x32_bf16(a,b,c,0,0,0);
}
__device__ __forceinline__ int xs_idx(int s,int c){ return s*256 + ((((c>>3)^(s&31))&31)<<3) + (c&7); }
__device__ __forceinline__ int wl_idx(int dm,int c){ return dm*256 + ((((c>>3)^(dm&31))&31)<<3) + (c&7); }
__device__ __forceinline__ void gload_lds16(const void* g, void* l){
  __builtin_amdgcn_global_load_lds((const __attribute__((address_space(1))) unsigned int*)g,
                                   (__attribute__((address_space(3))) unsigned int*)l, 16, 0, 0);
}

// ws layout (bytes):
//   [0, 393216)            wsW : 8 heads x (96x256) bf16 pre-swizzled
//   [393216, 524288)       wsWo: 8 oc x (32x256) bf16 pre-swizzled
//   [524288, +3*67108864)  Qw, Kw, Vw : [b][head][16384 pos][32 d] bf16
//   [201850880, +67108864) Ah  : [b][16384 pos][256 c] bf16, chunk-swizzled (^pos&31)
#define WS_OFF_AH 201850880ULL

__global__ __launch_bounds__(512,4)
void prep_w_kernel(const float* __restrict__ Wq, const float* __restrict__ Wk,
                   const float* __restrict__ Wv, const float* __restrict__ Wo,
                   unsigned short* __restrict__ wsW, unsigned short* __restrict__ wsWo){
  const int bid = blockIdx.x, t = threadIdx.x;
  if (bid < 96){
    int h = bid/12, seg = bid%12;
    int dm = seg*8 + (t>>6), c = (t&63)*4;
    const float* Wm = dm<32 ? Wq : (dm<64 ? Wk : Wv);
    const float4 w4 = *(const float4*)&Wm[(h*32 + (dm&31))*C_ + c];
    ushort4 pk = { f2bf(w4.x), f2bf(w4.y), f2bf(w4.z), f2bf(w4.w) };
    *(ushort4*)(wsW + h*24576 + wl_idx(dm, c)) = pk;
  } else {
    int q = bid - 96;
    int oc = q>>2, seg = q&3;
    int o = seg*8 + (t>>6), c = (t&63)*4;
    const float4 w4 = *(const float4*)&Wo[(oc*32+o)*C_ + c];
    ushort4 pk = { f2bf(w4.x), f2bf(w4.y), f2bf(w4.z), f2bf(w4.w) };
    *(ushort4*)(wsWo + oc*8192 + wl_idx(o, c)) = pk;
  }
}

// ---- proj5: proj4 structure, launch_bounds(512,2) so m=2 blocking doesn't spill.
// (512,4) capped VGPR at 64 -> ~25-reg spill (R8: FETCH+75MB, WRITE+47MB).
// At ~96-112 VGPR occupancy is 2 blocks/CU -- same as the 76.8KB LDS limit.
__global__ __launch_bounds__(512,2)
void proj5_kernel(const float* __restrict__ x,
                  const float* __restrict__ bq, const float* __restrict__ bk,
                  const float* __restrict__ bv,
                  const unsigned short* __restrict__ wsW,
                  unsigned short* __restrict__ Qw, unsigned short* __restrict__ Kw,
                  unsigned short* __restrict__ Vw){
  __shared__ __align__(16) char smem[76800];
  unsigned short* xs = (unsigned short*)smem;            // phase 0 only (64K)
  unsigned short* wl = (unsigned short*)smem;            // [96][256] swz (48K)
  unsigned short* rp = (unsigned short*)(smem + 49152);  // [128][104] (26.6K)

  const int tid = threadIdx.x;
  const int b = blockIdx.x >> 7, pt = blockIdx.x & 127;
  const size_t pos0 = (size_t)pt * 128;

  {  // stage x tile -> xs (bf16 swizzled [pos][c])
    const int cq = (tid>>5)*2, pl = (tid&31)*4;
    #pragma unroll
    for (int j=0;j<8;++j){
      int c0 = j*32 + cq;
      const float4 a0 = *(const float4*)&x[((size_t)(b*C_ + c0  ))*16384 + pos0 + pl];
      const float4 a1 = *(const float4*)&x[((size_t)(b*C_ + c0+1))*16384 + pos0 + pl];
      unsigned int p0 = (unsigned)f2bf(a0.x) | ((unsigned)f2bf(a1.x)<<16);
      unsigned int p1 = (unsigned)f2bf(a0.y) | ((unsigned)f2bf(a1.y)<<16);
      unsigned int p2 = (unsigned)f2bf(a0.z) | ((unsigned)f2bf(a1.z)<<16);
      unsigned int p3 = (unsigned)f2bf(a0.w) | ((unsigned)f2bf(a1.w)<<16);
      *(unsigned int*)&xs[xs_idx(pl+0, c0)] = p0;
      *(unsigned int*)&xs[xs_idx(pl+1, c0)] = p1;
      *(unsigned int*)&xs[xs_idx(pl+2, c0)] = p2;
      *(unsigned int*)&xs[xs_idx(pl+3, c0)] = p3;
    }
  }
  __syncthreads();                     // xs visible

  const int lane = tid&63, wv = tid>>6, lr = lane&15, lk = lane>>4;
  const int mbase = (wv&3)*2;          // this wave's two M-tiles
  const int nb    = (wv>>2)*3;         // this wave's n-tile base (0 or 3)
  v8s areg0[8], areg1[8];
  #pragma unroll
  for (int ks=0;ks<8;++ks){
    areg0[ks] = *(const v8s*)(xs + xs_idx((mbase  )*16+lr, ks*32+lk*8));
    areg1[ks] = *(const v8s*)(xs + xs_idx((mbase+1)*16+lr, ks*32+lk*8));
  }
  __syncthreads();                     // xs consumed; region becomes wl

  {  // issue wl(head 0)
    const char* wb = (const char*)wsW;
    for (int rIt=0;rIt<6;++rIt)
      gload_lds16(wb + (rIt*512+tid)*16, (char*)wl + (rIt*512+tid)*16);
  }

  const f32x4 zero4 = {0.f,0.f,0.f,0.f};
  const int wp = tid>>2, wch = tid&3;  // writeout mapping (block-wide)

  for (int h=0; h<HEADS_; ++h){
    __syncthreads();                   // A: wl(h) drained; rp(h-1) visible
    float bias_[3];
    #pragma unroll
    for (int ni=0;ni<3;++ni){
      int n = nb + ni;
      const float* bm = (n>>1)==0 ? bq : ((n>>1)==1 ? bk : bv);
      bias_[ni] = bm[h*32 + (n&1)*16 + lr];
    }
    // ---- writeout(h-1): issues here, overlaps MFMA below ----
    if (h > 0){
      v8s qd = *(const v8s*)&rp[wp*104 +      wch*8];
      v8s kd = *(const v8s*)&rp[wp*104 + 32 + wch*8];
      v8s vd = *(const v8s*)&rp[wp*104 + 64 + wch*8];
      size_t og = ((size_t)(b*HEADS_+(h-1))*16384 + pos0 + wp)*32 + wch*8;
      *(v8s*)(Qw + og) = qd;
      *(v8s*)(Kw + og) = kd;
      *(v8s*)(Vw + og) = vd;
    }
    // ---- projection MFMA: 3 n-tiles x 2 M-tiles x 8 ks ----
    f32x4 acc[3][2];
    #pragma unroll
    for (int ni=0;ni<3;++ni){ acc[ni][0]=zero4; acc[ni][1]=zero4; }
    #pragma unroll
    for (int ks=0;ks<8;++ks){
      int c0 = ks*32 + lk*8;
      #pragma unroll
      for (int ni=0;ni<3;++ni){
        v8s bb = *(const v8s*)(wl + wl_idx((nb+ni)*16+lr, c0));
        acc[ni][0] = mfma16(areg0[ks], bb, acc[ni][0]);
        acc[ni][1] = mfma16(areg1[ks], bb, acc[ni][1]);
      }
    }
    __syncthreads();                   // B: wl reads + rp reads done
    if (h < HEADS_-1){                 // prefetch wl(h+1)
      const char* wb = (const char*)wsW + (h+1)*49152;
      for (int rIt=0;rIt<6;++rIt)
        gload_lds16(wb + (rIt*512+tid)*16, (char*)wl + (rIt*512+tid)*16);
    }
    // ---- repack acc(h) -> rp (+bias, q scaled) ----
    #pragma unroll
    for (int ni=0;ni<3;++ni){
      int n = nb + ni;
      int dm = n*16 + lr;
      float bia = bias_[ni];
      #pragma unroll
      for (int mi=0;mi<2;++mi){
        #pragma unroll
        for (int rr=0;rr<4;++rr){
          int pos = (mbase+mi)*16 + lk*4 + rr;
          float val = acc[ni][mi][rr] + bia;
          if (n<2) val *= SCALE;
          rp[pos*104 + dm] = f2bf(val);
        }
      }
    }
  }
  __syncthreads();                     // rp(7) visible
  {
    v8s qd = *(const v8s*)&rp[wp*104 +      wch*8];
    v8s kd = *(const v8s*)&rp[wp*104 + 32 + wch*8];
    v8s vd = *(const v8s*)&rp[wp*104 + 64 + wch*8];
    size_t og = ((size_t)(b*HEADS_+7)*16384 + pos0 + wp)*32 + wch*8;
    *(v8s*)(Qw + og) = qd;
    *(v8s*)(Kw + og) = kd;
    *(v8s*)(Vw + og) = vd;
  }
}

// ---- attention (R4-proven): swapped QK^T, in-register PV, bf16 Ah output ----
template<int VERT>
__global__ __launch_bounds__(512,6)
void attn2_kernel(const unsigned short* __restrict__ Qw, const unsigned short* __restrict__ Kw,
                  const unsigned short* __restrict__ Vw, unsigned short* __restrict__ Ah){
  __shared__ __align__(16) char smem[37376];
  unsigned short* kl = (unsigned short*)smem;            // [128 key][40 d]
  unsigned short* Vt = (unsigned short*)(smem + 10240);  // [32 d][136 slot]
  float*          ob = (float*)(smem + 18944);           // [128 s][36 d]

  const int tid = threadIdx.x;
  int b, head, fix;
  if (VERT){ int xcd = blockIdx.x&7, rest = blockIdx.x>>3;
             fix = xcd*16 + (rest&15); head = (rest>>4)&7; b = rest>>7; }
  else     { head = blockIdx.x&7; fix = (blockIdx.x>>3)&127; b = blockIdx.x>>10; }
  const size_t tb = (size_t)(b*HEADS_+head)*16384*32;
  const int lane = tid&63, wvq = tid>>6, lr = lane&15, lk = lane>>4;
  const f32x4 zero4 = {0.f,0.f,0.f,0.f};

  {
    int pl = tid>>2, ch = tid&3;
    size_t g = tb + (VERT ? ((size_t)pl*128 + fix) : ((size_t)fix*128 + pl))*32 + ch*8;
    v8s kv = *(const v8s*)(Kw + g);
    v8s vv = *(const v8s*)(Vw + g);
    *(v8s*)&kl[pl*40 + ch*8] = kv;
    int slot = (pl & ~31) | (((pl>>2)&3)<<3) | (((pl>>4)&1)<<2) | (pl&3);
    #pragma unroll
    for (int j=0;j<8;++j) Vt[(ch*8+j)*136 + slot] = (unsigned short)vv[j];
  }
  const int posq = VERT ? (wvq*16+lr)*128 + fix : fix*128 + (wvq*16+lr);
  v8s qa = *(const v8s*)(Qw + tb + (size_t)posq*32 + lk*8);
  __syncthreads();

  f32x4 sc[8];
  #pragma unroll
  for (int kt=0;kt<8;++kt){
    v8s kb = *(const v8s*)&kl[(kt*16+lr)*40 + lk*8];
    sc[kt] = mfma16(kb, qa, zero4);
  }
  float mx = sc[0][0];
  #pragma unroll
  for (int kt=0;kt<8;++kt){
    #pragma unroll
    for (int rr=0;rr<4;++rr) mx = fmaxf(mx, sc[kt][rr]);
  }
  mx = fmaxf(mx, __shfl_xor(mx, 16));
  mx = fmaxf(mx, __shfl_xor(mx, 32));
  float sm = 0.f;
  #pragma unroll
  for (int kt=0;kt<8;++kt){
    #pragma unroll
    for (int rr=0;rr<4;++rr){ float p = __expf(sc[kt][rr]-mx); sc[kt][rr]=p; sm += p; }
  }
  sm += __shfl_xor(sm, 16);
  sm += __shfl_xor(sm, 32);
  const float rn = 1.f/sm;
  unsigned int pk[16];
  #pragma unroll
  for (int kt=0;kt<8;++kt){
    pk[kt*2  ] = (unsigned)f2bf(sc[kt][0]*rn) | ((unsigned)f2bf(sc[kt][1]*rn)<<16);
    pk[kt*2+1] = (unsigned)f2bf(sc[kt][2]*rn) | ((unsigned)f2bf(sc[kt][3]*rn)<<16);
  }
  f32x4 o0 = zero4, o1 = zero4;
  #pragma unroll
  for (int ks=0;ks<4;++ks){
    union { unsigned int u[4]; v8s v; } pa;
    pa.u[0]=pk[4*ks]; pa.u[1]=pk[4*ks+1]; pa.u[2]=pk[4*ks+2]; pa.u[3]=pk[4*ks+3];
    v8s v0 = *(const v8s*)&Vt[(     lr)*136 + ks*32 + lk*8];
    v8s v1 = *(const v8s*)&Vt[(16 + lr)*136 + ks*32 + lk*8];
    o0 = mfma16(pa.v, v0, o0);
    o1 = mfma16(pa.v, v1, o1);
  }
  #pragma unroll
  for (int rr=0;rr<4;++rr){
    int s = wvq*16 + lk*4 + rr;
    ob[s*36 + lr     ] = o0[rr];
    ob[s*36 + 16 + lr] = o1[rr];
  }
  {
    int row = wvq*16 + (lane>>2), jj = lane&3;
    f32x4 fa = *(const f32x4*)&ob[row*36 + jj*8];
    f32x4 fb = *(const f32x4*)&ob[row*36 + jj*8 + 4];
    int pos = VERT ? row*128 + fix : fix*128 + row;
    size_t ga = ((size_t)b*16384 + pos)*256 + (size_t)(((head*4+jj)^(pos&31))<<3);
    if (VERT){
      v8s prev = *(const v8s*)(Ah + ga);
      v8s outv;
      #pragma unroll
      for (int j=0;j<4;++j){
        outv[j]   = (short)f2bf(bf2f((unsigned short)prev[j])   + fa[j]);
        outv[4+j] = (short)f2bf(bf2f((unsigned short)prev[4+j]) + fb[j]);
      }
      *(v8s*)(Ah + ga) = outv;
    } else {
      v8s outv;
      #pragma unroll
      for (int j=0;j<4;++j){
        outv[j]   = (short)f2bf(fa[j]);
        outv[4+j] = (short)f2bf(fb[j]);
      }
      *(v8s*)(Ah + ga) = outv;
    }
  }
}

// ---- final: Ah via global_load_lds, GEMM Wo, +bias(direct) +x; 80KB -> 2 blk/CU ----
__global__ __launch_bounds__(512,4)
void final2_kernel(const float* __restrict__ x, const unsigned short* __restrict__ wsWo,
                   const float* __restrict__ bo, const unsigned short* __restrict__ Ah,
                   float* __restrict__ out)
{
  __shared__ __align__(16) char smem[81920];
  unsigned short* asl = (unsigned short*)smem;            // [128 pos][256 c] swz
  unsigned short* wol = (unsigned short*)(smem + 65536);  // [32 o][256 c] swz

  const int tid = threadIdx.x;
  const int b = blockIdx.x >> 7, pt = blockIdx.x & 127;
  {
    const char* ab = (const char*)(Ah + ((size_t)b*16384 + (size_t)pt*128)*256);
    for (int i=0;i<8;++i)
      gload_lds16(ab + (i*512+tid)*16, (char*)asl + (i*512+tid)*16);
  }
  const int lane = tid & 63, wv = tid >> 6;
  const int lr = lane & 15, lk = lane >> 4;
  const f32x4 zero4 = {0.f,0.f,0.f,0.f};

  for (int oc = 0; oc < 8; ++oc){
    {
      const char* wb = (const char*)wsWo + oc*16384;
      for (int rIt=0;rIt<2;++rIt)
        gload_lds16(wb + (rIt*512+tid)*16, (char*)wol + (rIt*512+tid)*16);
    }
    const float b0v = bo[oc*32 + lr], b1v = bo[oc*32 + 16 + lr];
    __syncthreads();

    f32x4 a0 = zero4, a1 = zero4;
    #pragma unroll
    for (int ks = 0; ks < 8; ++ks){
      int c0 = ks*32 + lk*8;
      v8s av = *(const v8s*)(asl + xs_idx(wv*16 + lr, c0));
      v8s b0 = *(const v8s*)(wol + wl_idx(     lr, c0));
      v8s b1 = *(const v8s*)(wol + wl_idx(16 + lr, c0));
      a0 = mfma16(av, b0, a0);
      a1 = mfma16(av, b1, a1);
    }
    {
      int base0 = ((b*C_ + oc*32 + lr)*HH)*WW + pt*128 + wv*16 + lk*4;
      f32x4 xv0 = *(const f32x4*)(x + base0);
      f32x4 xv1 = *(const f32x4*)(x + base0 + 16*HH*WW);
      f32x4 r0 = a0 + xv0 + b0v;
      f32x4 r1 = a1 + xv1 + b1v;
      *(f32x4*)(out + base0) = r0;
      *(f32x4*)(out + base0 + 16*HH*WW) = r1;
    }
    __syncthreads();
  }
}

extern "C" void kernel_launch(void* const* d_in, const int* in_sizes, int n_in,
                              void* d_out, int out_size, void* d_ws, size_t ws_size,
                              hipStream_t stream) {
  const float* x  = (const float*)d_in[0];
  const float* Wq = (const float*)d_in[1];
  const float* bq = (const float*)d_in[2];
  const float* Wk = (const float*)d_in[3];
  const float* bk = (const float*)d_in[4];
  const float* Wv = (const float*)d_in[5];
  const float* bv = (const float*)d_in[6];
  const float* Wo = (const float*)d_in[7];
  const float* bo = (const float*)d_in[8];
  float* out = (float*)d_out;

  unsigned short* wsW  = (unsigned short*)d_ws;
  unsigned short* wsWo = (unsigned short*)((char*)d_ws + 393216);
  unsigned short* Qw   = (unsigned short*)((char*)d_ws + 524288);
  unsigned short* Kw   = Qw + 33554432;
  unsigned short* Vw   = Kw + 33554432;
  unsigned short* Ah   = (unsigned short*)((char*)d_ws + WS_OFF_AH);

  prep_w_kernel<<<dim3(128),  dim3(512), 0, stream>>>(Wq, Wk, Wv, Wo, wsW, wsWo);
  proj5_kernel <<<dim3(1024), dim3(512), 0, stream>>>(x, bq, bk, bv, wsW, Qw, Kw, Vw);
  attn2_kernel<0><<<dim3(8192), dim3(512), 0, stream>>>(Qw, Kw, Vw, Ah);
  attn2_kernel<1><<<dim3(8192), dim3(512), 0, stream>>>(Qw, Kw, Vw, Ah);
  final2_kernel<<<dim3(1024), dim3(512), 0, stream>>>(x, wsWo, bo, Ah, out);
}

// Round 10
// 270.330 us; speedup vs baseline: 1.4504x; 1.0739x over previous
//
#include <hip/hip_runtime.h>

#define B_ 8
#define C_ 256
#define HH 128
#define WW 128
#define HEADS_ 8
#define SCALE 0.17677669529663687f   // 32^-0.5

typedef short v8s __attribute__((ext_vector_type(8)));
typedef float f32x4 __attribute__((ext_vector_type(4)));

__device__ __forceinline__ unsigned short f2bf(float f){
  unsigned int u = __float_as_uint(f);
  u += 0x7FFFu + ((u>>16)&1u);
  return (unsigned short)(u>>16);
}
__device__ __forceinline__ float bf2f(unsigned short s){ return __uint_as_float(((unsigned int)s)<<16); }
__device__ __forceinline__ f32x4 mfma16(v8s a, v8s b, f32x4 c){
  return __builtin_amdgcn_mfma_f32_16x16x32_bf16(a,b,c,0,0,0);
}
__device__ __forceinline__ int xs_idx(int s,int c){ return s*256 + ((((c>>3)^(s&31))&31)<<3) + (c&7); }
__device__ __forceinline__ int wl_idx(int dm,int c){ return dm*256 + ((((c>>3)^(dm&31))&31)<<3) + (c&7); }
__device__ __forceinline__ void gload_lds16(const void* g, void* l){
  __builtin_amdgcn_global_load_lds((const __attribute__((address_space(1))) unsigned int*)g,
                                   (__attribute__((address_space(3))) unsigned int*)l, 16, 0, 0);
}

// ws layout (bytes):
//   [0, 393216)            wsW : 8 heads x (96x256) bf16 pre-swizzled
//   [393216, 524288)       wsWo: 8 oc x (32x256) bf16 pre-swizzled
//   [524288, +3*67108864)  Qw, Kw, Vw : [b][head][16384 pos][32 d] bf16
//   [201850880, +67108864) Ah  : [b][16384 pos][256 c] bf16, chunk-swizzled (^pos&31)
#define WS_OFF_AH 201850880ULL

__global__ __launch_bounds__(512,4)
void prep_w_kernel(const float* __restrict__ Wq, const float* __restrict__ Wk,
                   const float* __restrict__ Wv, const float* __restrict__ Wo,
                   unsigned short* __restrict__ wsW, unsigned short* __restrict__ wsWo){
  const int bid = blockIdx.x, t = threadIdx.x;
  if (bid < 96){
    int h = bid/12, seg = bid%12;
    int dm = seg*8 + (t>>6), c = (t&63)*4;
    const float* Wm = dm<32 ? Wq : (dm<64 ? Wk : Wv);
    const float4 w4 = *(const float4*)&Wm[(h*32 + (dm&31))*C_ + c];
    ushort4 pk = { f2bf(w4.x), f2bf(w4.y), f2bf(w4.z), f2bf(w4.w) };
    *(ushort4*)(wsW + h*24576 + wl_idx(dm, c)) = pk;
  } else {
    int q = bid - 96;
    int oc = q>>2, seg = q&3;
    int o = seg*8 + (t>>6), c = (t&63)*4;
    const float4 w4 = *(const float4*)&Wo[(oc*32+o)*C_ + c];
    ushort4 pk = { f2bf(w4.x), f2bf(w4.y), f2bf(w4.z), f2bf(w4.w) };
    *(ushort4*)(wsWo + oc*8192 + wl_idx(o, c)) = pk;
  }
}

// ---- proj6: R6 proj3 (m=1, 2 blocks/CU at 76.8KB LDS, VGPR<=64) + bias-direct ----
__global__ __launch_bounds__(512,4)
void proj6_kernel(const float* __restrict__ x,
                  const float* __restrict__ bq, const float* __restrict__ bk,
                  const float* __restrict__ bv,
                  const unsigned short* __restrict__ wsW,
                  unsigned short* __restrict__ Qw, unsigned short* __restrict__ Kw,
                  unsigned short* __restrict__ Vw){
  __shared__ __align__(16) char smem[76800];
  unsigned short* xs = (unsigned short*)smem;            // phase 0 only (64K)
  unsigned short* wl = (unsigned short*)smem;            // [96][256] swz (48K)
  unsigned short* rp = (unsigned short*)(smem + 49152);  // [128][104] (26.6K)

  const int tid = threadIdx.x;
  const int b = blockIdx.x >> 7, pt = blockIdx.x & 127;
  const size_t pos0 = (size_t)pt * 128;

  {  // stage x tile -> xs (bf16 swizzled [pos][c]); coalesced float4 along pos
    const int cq = (tid>>5)*2, pl = (tid&31)*4;
    #pragma unroll
    for (int j=0;j<8;++j){
      int c0 = j*32 + cq;
      const float4 a0 = *(const float4*)&x[((size_t)(b*C_ + c0  ))*16384 + pos0 + pl];
      const float4 a1 = *(const float4*)&x[((size_t)(b*C_ + c0+1))*16384 + pos0 + pl];
      unsigned int p0 = (unsigned)f2bf(a0.x) | ((unsigned)f2bf(a1.x)<<16);
      unsigned int p1 = (unsigned)f2bf(a0.y) | ((unsigned)f2bf(a1.y)<<16);
      unsigned int p2 = (unsigned)f2bf(a0.z) | ((unsigned)f2bf(a1.z)<<16);
      unsigned int p3 = (unsigned)f2bf(a0.w) | ((unsigned)f2bf(a1.w)<<16);
      *(unsigned int*)&xs[xs_idx(pl+0, c0)] = p0;
      *(unsigned int*)&xs[xs_idx(pl+1, c0)] = p1;
      *(unsigned int*)&xs[xs_idx(pl+2, c0)] = p2;
      *(unsigned int*)&xs[xs_idx(pl+3, c0)] = p3;
    }
  }
  __syncthreads();                     // xs visible

  const int lane = tid&63, wv = tid>>6, lr = lane&15, lk = lane>>4;
  v8s areg[8];
  #pragma unroll
  for (int ks=0;ks<8;++ks) areg[ks] = *(const v8s*)(xs + xs_idx(wv*16+lr, ks*32+lk*8));
  __syncthreads();                     // xs consumed; region becomes wl

  {  // issue wl(head 0)
    const char* wb = (const char*)wsW;
    for (int rIt=0;rIt<6;++rIt)
      gload_lds16(wb + (rIt*512+tid)*16, (char*)wl + (rIt*512+tid)*16);
  }

  const f32x4 zero4 = {0.f,0.f,0.f,0.f};
  for (int h=0; h<HEADS_; ++h){
    __syncthreads();                   // A: wl(h) ready (vmcnt drained); rp free
    f32x4 acc[6];
    #pragma unroll
    for (int n=0;n<6;++n) acc[n]=zero4;
    #pragma unroll
    for (int ks=0;ks<8;++ks){
      int c0 = ks*32 + lk*8;
      #pragma unroll
      for (int n=0;n<6;++n){
        v8s bb = *(const v8s*)(wl + wl_idx(n*16+lr, c0));
        acc[n] = mfma16(areg[ks], bb, acc[n]);
      }
    }
    __syncthreads();                   // B: wl reads done
    if (h < HEADS_-1){                 // prefetch wl(h+1)
      const char* wb = (const char*)wsW + (h+1)*49152;
      for (int rIt=0;rIt<6;++rIt)
        gload_lds16(wb + (rIt*512+tid)*16, (char*)wl + (rIt*512+tid)*16);
    }
    // ---- repack acc(h) -> rp (+bias direct from global, q scaled) ----
    #pragma unroll
    for (int n=0;n<6;++n){
      int dm = n*16+lr;
      const float* bm = (n>>1)==0 ? bq : ((n>>1)==1 ? bk : bv);
      float bia = bm[h*32 + (n&1)*16 + lr];
      #pragma unroll
      for (int rr=0;rr<4;++rr){
        int pos = wv*16 + lk*4 + rr;
        float val = acc[n][rr] + bia;
        if (n<2) val *= SCALE;
        rp[pos*104 + dm] = f2bf(val);
      }
    }
    __syncthreads();                   // C: rp visible
    {
      int p = tid>>2, ch = tid&3;
      v8s qd = *(const v8s*)&rp[p*104 +      ch*8];
      v8s kd = *(const v8s*)&rp[p*104 + 32 + ch*8];
      v8s vd = *(const v8s*)&rp[p*104 + 64 + ch*8];
      size_t og = ((size_t)(b*HEADS_+h)*16384 + pos0 + p)*32 + ch*8;
      *(v8s*)(Qw + og) = qd;
      *(v8s*)(Kw + og) = kd;
      *(v8s*)(Vw + og) = vd;
    }
  }
}

// ---- attention (R4-proven): swapped QK^T, in-register PV, bf16 Ah output ----
template<int VERT>
__global__ __launch_bounds__(512,6)
void attn2_kernel(const unsigned short* __restrict__ Qw, const unsigned short* __restrict__ Kw,
                  const unsigned short* __restrict__ Vw, unsigned short* __restrict__ Ah){
  __shared__ __align__(16) char smem[37376];
  unsigned short* kl = (unsigned short*)smem;            // [128 key][40 d]
  unsigned short* Vt = (unsigned short*)(smem + 10240);  // [32 d][136 slot]
  float*          ob = (float*)(smem + 18944);           // [128 s][36 d]

  const int tid = threadIdx.x;
  int b, head, fix;
  if (VERT){ int xcd = blockIdx.x&7, rest = blockIdx.x>>3;
             fix = xcd*16 + (rest&15); head = (rest>>4)&7; b = rest>>7; }
  else     { head = blockIdx.x&7; fix = (blockIdx.x>>3)&127; b = blockIdx.x>>10; }
  const size_t tb = (size_t)(b*HEADS_+head)*16384*32;
  const int lane = tid&63, wvq = tid>>6, lr = lane&15, lk = lane>>4;
  const f32x4 zero4 = {0.f,0.f,0.f,0.f};

  {
    int pl = tid>>2, ch = tid&3;
    size_t g = tb + (VERT ? ((size_t)pl*128 + fix) : ((size_t)fix*128 + pl))*32 + ch*8;
    v8s kv = *(const v8s*)(Kw + g);
    v8s vv = *(const v8s*)(Vw + g);
    *(v8s*)&kl[pl*40 + ch*8] = kv;
    int slot = (pl & ~31) | (((pl>>2)&3)<<3) | (((pl>>4)&1)<<2) | (pl&3);
    #pragma unroll
    for (int j=0;j<8;++j) Vt[(ch*8+j)*136 + slot] = (unsigned short)vv[j];
  }
  const int posq = VERT ? (wvq*16+lr)*128 + fix : fix*128 + (wvq*16+lr);
  v8s qa = *(const v8s*)(Qw + tb + (size_t)posq*32 + lk*8);
  __syncthreads();

  f32x4 sc[8];
  #pragma unroll
  for (int kt=0;kt<8;++kt){
    v8s kb = *(const v8s*)&kl[(kt*16+lr)*40 + lk*8];
    sc[kt] = mfma16(kb, qa, zero4);
  }
  float mx = sc[0][0];
  #pragma unroll
  for (int kt=0;kt<8;++kt){
    #pragma unroll
    for (int rr=0;rr<4;++rr) mx = fmaxf(mx, sc[kt][rr]);
  }
  mx = fmaxf(mx, __shfl_xor(mx, 16));
  mx = fmaxf(mx, __shfl_xor(mx, 32));
  float sm = 0.f;
  #pragma unroll
  for (int kt=0;kt<8;++kt){
    #pragma unroll
    for (int rr=0;rr<4;++rr){ float p = __expf(sc[kt][rr]-mx); sc[kt][rr]=p; sm += p; }
  }
  sm += __shfl_xor(sm, 16);
  sm += __shfl_xor(sm, 32);
  const float rn = 1.f/sm;
  unsigned int pk[16];
  #pragma unroll
  for (int kt=0;kt<8;++kt){
    pk[kt*2  ] = (unsigned)f2bf(sc[kt][0]*rn) | ((unsigned)f2bf(sc[kt][1]*rn)<<16);
    pk[kt*2+1] = (unsigned)f2bf(sc[kt][2]*rn) | ((unsigned)f2bf(sc[kt][3]*rn)<<16);
  }
  f32x4 o0 = zero4, o1 = zero4;
  #pragma unroll
  for (int ks=0;ks<4;++ks){
    union { unsigned int u[4]; v8s v; } pa;
    pa.u[0]=pk[4*ks]; pa.u[1]=pk[4*ks+1]; pa.u[2]=pk[4*ks+2]; pa.u[3]=pk[4*ks+3];
    v8s v0 = *(const v8s*)&Vt[(     lr)*136 + ks*32 + lk*8];
    v8s v1 = *(const v8s*)&Vt[(16 + lr)*136 + ks*32 + lk*8];
    o0 = mfma16(pa.v, v0, o0);
    o1 = mfma16(pa.v, v1, o1);
  }
  #pragma unroll
  for (int rr=0;rr<4;++rr){
    int s = wvq*16 + lk*4 + rr;
    ob[s*36 + lr     ] = o0[rr];
    ob[s*36 + 16 + lr] = o1[rr];
  }
  {
    int row = wvq*16 + (lane>>2), jj = lane&3;
    f32x4 fa = *(const f32x4*)&ob[row*36 + jj*8];
    f32x4 fb = *(const f32x4*)&ob[row*36 + jj*8 + 4];
    int pos = VERT ? row*128 + fix : fix*128 + row;
    size_t ga = ((size_t)b*16384 + pos)*256 + (size_t)(((head*4+jj)^(pos&31))<<3);
    if (VERT){
      v8s prev = *(const v8s*)(Ah + ga);
      v8s outv;
      #pragma unroll
      for (int j=0;j<4;++j){
        outv[j]   = (short)f2bf(bf2f((unsigned short)prev[j])   + fa[j]);
        outv[4+j] = (short)f2bf(bf2f((unsigned short)prev[4+j]) + fb[j]);
      }
      *(v8s*)(Ah + ga) = outv;
    } else {
      v8s outv;
      #pragma unroll
      for (int j=0;j<4;++j){
        outv[j]   = (short)f2bf(fa[j]);
        outv[4+j] = (short)f2bf(fb[j]);
      }
      *(v8s*)(Ah + ga) = outv;
    }
  }
}

// ---- final: Ah via global_load_lds, GEMM Wo, +bias(direct) +x; 80KB -> 2 blk/CU ----
__global__ __launch_bounds__(512,4)
void final2_kernel(const float* __restrict__ x, const unsigned short* __restrict__ wsWo,
                   const float* __restrict__ bo, const unsigned short* __restrict__ Ah,
                   float* __restrict__ out)
{
  __shared__ __align__(16) char smem[81920];
  unsigned short* asl = (unsigned short*)smem;            // [128 pos][256 c] swz
  unsigned short* wol = (unsigned short*)(smem + 65536);  // [32 o][256 c] swz

  const int tid = threadIdx.x;
  const int b = blockIdx.x >> 7, pt = blockIdx.x & 127;
  {
    const char* ab = (const char*)(Ah + ((size_t)b*16384 + (size_t)pt*128)*256);
    for (int i=0;i<8;++i)
      gload_lds16(ab + (i*512+tid)*16, (char*)asl + (i*512+tid)*16);
  }
  const int lane = tid & 63, wv = tid >> 6;
  const int lr = lane & 15, lk = lane >> 4;
  const f32x4 zero4 = {0.f,0.f,0.f,0.f};

  for (int oc = 0; oc < 8; ++oc){
    {
      const char* wb = (const char*)wsWo + oc*16384;
      for (int rIt=0;rIt<2;++rIt)
        gload_lds16(wb + (rIt*512+tid)*16, (char*)wol + (rIt*512+tid)*16);
    }
    const float b0v = bo[oc*32 + lr], b1v = bo[oc*32 + 16 + lr];
    __syncthreads();

    f32x4 a0 = zero4, a1 = zero4;
    #pragma unroll
    for (int ks = 0; ks < 8; ++ks){
      int c0 = ks*32 + lk*8;
      v8s av = *(const v8s*)(asl + xs_idx(wv*16 + lr, c0));
      v8s b0 = *(const v8s*)(wol + wl_idx(     lr, c0));
      v8s b1 = *(const v8s*)(wol + wl_idx(16 + lr, c0));
      a0 = mfma16(av, b0, a0);
      a1 = mfma16(av, b1, a1);
    }
    {
      int base0 = ((b*C_ + oc*32 + lr)*HH)*WW + pt*128 + wv*16 + lk*4;
      f32x4 xv0 = *(const f32x4*)(x + base0);
      f32x4 xv1 = *(const f32x4*)(x + base0 + 16*HH*WW);
      f32x4 r0 = a0 + xv0 + b0v;
      f32x4 r1 = a1 + xv1 + b1v;
      *(f32x4*)(out + base0) = r0;
      *(f32x4*)(out + base0 + 16*HH*WW) = r1;
    }
    __syncthreads();
  }
}

extern "C" void kernel_launch(void* const* d_in, const int* in_sizes, int n_in,
                              void* d_out, int out_size, void* d_ws, size_t ws_size,
                              hipStream_t stream) {
  const float* x  = (const float*)d_in[0];
  const float* Wq = (const float*)d_in[1];
  const float* bq = (const float*)d_in[2];
  const float* Wk = (const float*)d_in[3];
  const float* bk = (const float*)d_in[4];
  const float* Wv = (const float*)d_in[5];
  const float* bv = (const float*)d_in[6];
  const float* Wo = (const float*)d_in[7];
  const float* bo = (const float*)d_in[8];
  float* out = (float*)d_out;

  unsigned short* wsW  = (unsigned short*)d_ws;
  unsigned short* wsWo = (unsigned short*)((char*)d_ws + 393216);
  unsigned short* Qw   = (unsigned short*)((char*)d_ws + 524288);
  unsigned short* Kw   = Qw + 33554432;
  unsigned short* Vw   = Kw + 33554432;
  unsigned short* Ah   = (unsigned short*)((char*)d_ws + WS_OFF_AH);

  prep_w_kernel<<<dim3(128),  dim3(512), 0, stream>>>(Wq, Wk, Wv, Wo, wsW, wsWo);
  proj6_kernel <<<dim3(1024), dim3(512), 0, stream>>>(x, bq, bk, bv, wsW, Qw, Kw, Vw);
  attn2_kernel<0><<<dim3(8192), dim3(512), 0, stream>>>(Qw, Kw, Vw, Ah);
  attn2_kernel<1><<<dim3(8192), dim3(512), 0, stream>>>(Qw, Kw, Vw, Ah);
  final2_kernel<<<dim3(1024), dim3(512), 0, stream>>>(x, wsWo, bo, Ah, out);
}

// Round 11
// 267.427 us; speedup vs baseline: 1.4662x; 1.0109x over previous
//
#include <hip/hip_runtime.h>

#define B_ 8
#define C_ 256
#define HH 128
#define WW 128
#define HEADS_ 8
#define SCALE 0.17677669529663687f   // 32^-0.5

typedef short v8s __attribute__((ext_vector_type(8)));
typedef float f32x4 __attribute__((ext_vector_type(4)));

__device__ __forceinline__ unsigned short f2bf(float f){
  unsigned int u = __float_as_uint(f);
  u += 0x7FFFu + ((u>>16)&1u);
  return (unsigned short)(u>>16);
}
__device__ __forceinline__ float bf2f(unsigned short s){ return __uint_as_float(((unsigned int)s)<<16); }
__device__ __forceinline__ f32x4 mfma16(v8s a, v8s b, f32x4 c){
  return __builtin_amdgcn_mfma_f32_16x16x32_bf16(a,b,c,0,0,0);
}
__device__ __forceinline__ int xs_idx(int s,int c){ return s*256 + ((((c>>3)^(s&31))&31)<<3) + (c&7); }
__device__ __forceinline__ int wl_idx(int dm,int c){ return dm*256 + ((((c>>3)^(dm&31))&31)<<3) + (c&7); }
__device__ __forceinline__ void gload_lds16(const void* g, void* l){
  __builtin_amdgcn_global_load_lds((const __attribute__((address_space(1))) unsigned int*)g,
                                   (__attribute__((address_space(3))) unsigned int*)l, 16, 0, 0);
}

// ws layout (bytes):
//   [0, 393216)            wsW : 8 heads x (96x256) bf16 pre-swizzled
//   [393216, 524288)       wsWo: 8 oc x (32x256) bf16 pre-swizzled, c-dim pi-permuted
//   [524288, +3*67108864)  Qw, Kw, Vw : [b][head][16384 pos][32 d(pi)] bf16
//   [201850880, +67108864) Ah  : [b][16384 pos][256 c(pi)] bf16, chunk-swizzled
// pi-permutation within each head's 32 d: slot i holds true d = (i&1)*16 + (i>>1).
// q,k share pi (QK^T invariant); V's pi is matched by wsWo's permuted columns.
#define WS_OFF_AH 201850880ULL

__global__ __launch_bounds__(512,4)
void prep_w_kernel(const float* __restrict__ Wq, const float* __restrict__ Wk,
                   const float* __restrict__ Wv, const float* __restrict__ Wo,
                   unsigned short* __restrict__ wsW, unsigned short* __restrict__ wsWo){
  const int bid = blockIdx.x, t = threadIdx.x;
  if (bid < 96){
    int h = bid/12, seg = bid%12;
    int dm = seg*8 + (t>>6), c = (t&63)*4;
    const float* Wm = dm<32 ? Wq : (dm<64 ? Wk : Wv);
    const float4 w4 = *(const float4*)&Wm[(h*32 + (dm&31))*C_ + c];
    ushort4 pk = { f2bf(w4.x), f2bf(w4.y), f2bf(w4.z), f2bf(w4.w) };
    *(ushort4*)(wsW + h*24576 + wl_idx(dm, c)) = pk;
  } else {
    int q = bid - 96;
    int oc = q>>2, seg = q&3;
    int o = seg*8 + (t>>6), cs = (t&63)*4;   // cs = contraction slot base
    // slot s -> true channel: (s & ~31) | ((s&1)<<4) | ((s&31)>>1)
    float w[4];
    #pragma unroll
    for (int j=0;j<4;++j){
      int s = cs + j;
      int ctrue = (s & ~31) | ((s&1)<<4) | ((s&31)>>1);
      w[j] = Wo[(oc*32+o)*C_ + ctrue];
    }
    ushort4 pk = { f2bf(w[0]), f2bf(w[1]), f2bf(w[2]), f2bf(w[3]) };
    *(ushort4*)(wsWo + oc*8192 + wl_idx(o, cs)) = pk;
  }
}

// ---- proj7: proj6 + pi-permuted packed repack (12 b32 writes vs 24 b16) ----
__global__ __launch_bounds__(512,4)
void proj7_kernel(const float* __restrict__ x,
                  const float* __restrict__ bq, const float* __restrict__ bk,
                  const float* __restrict__ bv,
                  const unsigned short* __restrict__ wsW,
                  unsigned short* __restrict__ Qw, unsigned short* __restrict__ Kw,
                  unsigned short* __restrict__ Vw){
  __shared__ __align__(16) char smem[76800];
  unsigned short* xs = (unsigned short*)smem;            // phase 0 only (64K)
  unsigned short* wl = (unsigned short*)smem;            // [96][256] swz (48K)
  unsigned short* rp = (unsigned short*)(smem + 49152);  // [128][104] (26.6K)

  const int tid = threadIdx.x;
  const int b = blockIdx.x >> 7, pt = blockIdx.x & 127;
  const size_t pos0 = (size_t)pt * 128;

  {  // stage x tile -> xs (bf16 swizzled [pos][c]); coalesced float4 along pos
    const int cq = (tid>>5)*2, pl = (tid&31)*4;
    #pragma unroll
    for (int j=0;j<8;++j){
      int c0 = j*32 + cq;
      const float4 a0 = *(const float4*)&x[((size_t)(b*C_ + c0  ))*16384 + pos0 + pl];
      const float4 a1 = *(const float4*)&x[((size_t)(b*C_ + c0+1))*16384 + pos0 + pl];
      unsigned int p0 = (unsigned)f2bf(a0.x) | ((unsigned)f2bf(a1.x)<<16);
      unsigned int p1 = (unsigned)f2bf(a0.y) | ((unsigned)f2bf(a1.y)<<16);
      unsigned int p2 = (unsigned)f2bf(a0.z) | ((unsigned)f2bf(a1.z)<<16);
      unsigned int p3 = (unsigned)f2bf(a0.w) | ((unsigned)f2bf(a1.w)<<16);
      *(unsigned int*)&xs[xs_idx(pl+0, c0)] = p0;
      *(unsigned int*)&xs[xs_idx(pl+1, c0)] = p1;
      *(unsigned int*)&xs[xs_idx(pl+2, c0)] = p2;
      *(unsigned int*)&xs[xs_idx(pl+3, c0)] = p3;
    }
  }
  __syncthreads();                     // xs visible

  const int lane = tid&63, wv = tid>>6, lr = lane&15, lk = lane>>4;
  v8s areg[8];
  #pragma unroll
  for (int ks=0;ks<8;++ks) areg[ks] = *(const v8s*)(xs + xs_idx(wv*16+lr, ks*32+lk*8));
  __syncthreads();                     // xs consumed; region becomes wl

  {  // issue wl(head 0)
    const char* wb = (const char*)wsW;
    for (int rIt=0;rIt<6;++rIt)
      gload_lds16(wb + (rIt*512+tid)*16, (char*)wl + (rIt*512+tid)*16);
  }

  const f32x4 zero4 = {0.f,0.f,0.f,0.f};
  for (int h=0; h<HEADS_; ++h){
    __syncthreads();                   // A: wl(h) ready (vmcnt drained); rp free
    f32x4 acc[6];
    #pragma unroll
    for (int n=0;n<6;++n) acc[n]=zero4;
    #pragma unroll
    for (int ks=0;ks<8;++ks){
      int c0 = ks*32 + lk*8;
      #pragma unroll
      for (int n=0;n<6;++n){
        v8s bb = *(const v8s*)(wl + wl_idx(n*16+lr, c0));
        acc[n] = mfma16(areg[ks], bb, acc[n]);
      }
    }
    __syncthreads();                   // B: wl reads done
    if (h < HEADS_-1){                 // prefetch wl(h+1)
      const char* wb = (const char*)wsW + (h+1)*49152;
      for (int rIt=0;rIt<6;++rIt)
        gload_lds16(wb + (rIt*512+tid)*16, (char*)wl + (rIt*512+tid)*16);
    }
    // ---- repack acc(h) -> rp, pi-packed: slot(g, lr*2+(n&1)) gets d=(n&1)*16+lr ----
    #pragma unroll
    for (int g=0; g<3; ++g){
      const float* bm = g==0 ? bq : (g==1 ? bk : bv);
      float bv0 = bm[h*32 + lr];        // n = 2g  (true d = lr)
      float bv1 = bm[h*32 + 16 + lr];   // n = 2g+1 (true d = 16+lr)
      #pragma unroll
      for (int rr=0;rr<4;++rr){
        int pos = wv*16 + lk*4 + rr;
        float v0 = acc[2*g  ][rr] + bv0;
        float v1 = acc[2*g+1][rr] + bv1;
        if (g==0){ v0 *= SCALE; v1 *= SCALE; }
        unsigned int pkv = (unsigned)f2bf(v0) | ((unsigned)f2bf(v1)<<16);
        *(unsigned int*)&rp[pos*104 + g*32 + lr*2] = pkv;
      }
    }
    __syncthreads();                   // C: rp visible
    {
      int p = tid>>2, ch = tid&3;
      v8s qd = *(const v8s*)&rp[p*104 +      ch*8];
      v8s kd = *(const v8s*)&rp[p*104 + 32 + ch*8];
      v8s vd = *(const v8s*)&rp[p*104 + 64 + ch*8];
      size_t og = ((size_t)(b*HEADS_+h)*16384 + pos0 + p)*32 + ch*8;
      *(v8s*)(Qw + og) = qd;
      *(v8s*)(Kw + og) = kd;
      *(v8s*)(Vw + og) = vd;
    }
  }
}

// ---- attention (R4-proven, d-order opaque): swapped QK^T, in-reg PV, Ah out ----
template<int VERT>
__global__ __launch_bounds__(512,6)
void attn2_kernel(const unsigned short* __restrict__ Qw, const unsigned short* __restrict__ Kw,
                  const unsigned short* __restrict__ Vw, unsigned short* __restrict__ Ah){
  __shared__ __align__(16) char smem[37376];
  unsigned short* kl = (unsigned short*)smem;            // [128 key][40 d]
  unsigned short* Vt = (unsigned short*)(smem + 10240);  // [32 d][136 slot]
  float*          ob = (float*)(smem + 18944);           // [128 s][36 d]

  const int tid = threadIdx.x;
  int b, head, fix;
  if (VERT){ int xcd = blockIdx.x&7, rest = blockIdx.x>>3;
             fix = xcd*16 + (rest&15); head = (rest>>4)&7; b = rest>>7; }
  else     { head = blockIdx.x&7; fix = (blockIdx.x>>3)&127; b = blockIdx.x>>10; }
  const size_t tb = (size_t)(b*HEADS_+head)*16384*32;
  const int lane = tid&63, wvq = tid>>6, lr = lane&15, lk = lane>>4;
  const f32x4 zero4 = {0.f,0.f,0.f,0.f};

  {
    int pl = tid>>2, ch = tid&3;
    size_t g = tb + (VERT ? ((size_t)pl*128 + fix) : ((size_t)fix*128 + pl))*32 + ch*8;
    v8s kv = *(const v8s*)(Kw + g);
    v8s vv = *(const v8s*)(Vw + g);
    *(v8s*)&kl[pl*40 + ch*8] = kv;
    int slot = (pl & ~31) | (((pl>>2)&3)<<3) | (((pl>>4)&1)<<2) | (pl&3);
    #pragma unroll
    for (int j=0;j<8;++j) Vt[(ch*8+j)*136 + slot] = (unsigned short)vv[j];
  }
  const int posq = VERT ? (wvq*16+lr)*128 + fix : fix*128 + (wvq*16+lr);
  v8s qa = *(const v8s*)(Qw + tb + (size_t)posq*32 + lk*8);
  __syncthreads();

  f32x4 sc[8];
  #pragma unroll
  for (int kt=0;kt<8;++kt){
    v8s kb = *(const v8s*)&kl[(kt*16+lr)*40 + lk*8];
    sc[kt] = mfma16(kb, qa, zero4);
  }
  float mx = sc[0][0];
  #pragma unroll
  for (int kt=0;kt<8;++kt){
    #pragma unroll
    for (int rr=0;rr<4;++rr) mx = fmaxf(mx, sc[kt][rr]);
  }
  mx = fmaxf(mx, __shfl_xor(mx, 16));
  mx = fmaxf(mx, __shfl_xor(mx, 32));
  float sm = 0.f;
  #pragma unroll
  for (int kt=0;kt<8;++kt){
    #pragma unroll
    for (int rr=0;rr<4;++rr){ float p = __expf(sc[kt][rr]-mx); sc[kt][rr]=p; sm += p; }
  }
  sm += __shfl_xor(sm, 16);
  sm += __shfl_xor(sm, 32);
  const float rn = 1.f/sm;
  unsigned int pk[16];
  #pragma unroll
  for (int kt=0;kt<8;++kt){
    pk[kt*2  ] = (unsigned)f2bf(sc[kt][0]*rn) | ((unsigned)f2bf(sc[kt][1]*rn)<<16);
    pk[kt*2+1] = (unsigned)f2bf(sc[kt][2]*rn) | ((unsigned)f2bf(sc[kt][3]*rn)<<16);
  }
  f32x4 o0 = zero4, o1 = zero4;
  #pragma unroll
  for (int ks=0;ks<4;++ks){
    union { unsigned int u[4]; v8s v; } pa;
    pa.u[0]=pk[4*ks]; pa.u[1]=pk[4*ks+1]; pa.u[2]=pk[4*ks+2]; pa.u[3]=pk[4*ks+3];
    v8s v0 = *(const v8s*)&Vt[(     lr)*136 + ks*32 + lk*8];
    v8s v1 = *(const v8s*)&Vt[(16 + lr)*136 + ks*32 + lk*8];
    o0 = mfma16(pa.v, v0, o0);
    o1 = mfma16(pa.v, v1, o1);
  }
  #pragma unroll
  for (int rr=0;rr<4;++rr){
    int s = wvq*16 + lk*4 + rr;
    ob[s*36 + lr     ] = o0[rr];
    ob[s*36 + 16 + lr] = o1[rr];
  }
  {
    int row = wvq*16 + (lane>>2), jj = lane&3;
    f32x4 fa = *(const f32x4*)&ob[row*36 + jj*8];
    f32x4 fb = *(const f32x4*)&ob[row*36 + jj*8 + 4];
    int pos = VERT ? row*128 + fix : fix*128 + row;
    size_t ga = ((size_t)b*16384 + pos)*256 + (size_t)(((head*4+jj)^(pos&31))<<3);
    if (VERT){
      v8s prev = *(const v8s*)(Ah + ga);
      v8s outv;
      #pragma unroll
      for (int j=0;j<4;++j){
        outv[j]   = (short)f2bf(bf2f((unsigned short)prev[j])   + fa[j]);
        outv[4+j] = (short)f2bf(bf2f((unsigned short)prev[4+j]) + fb[j]);
      }
      *(v8s*)(Ah + ga) = outv;
    } else {
      v8s outv;
      #pragma unroll
      for (int j=0;j<4;++j){
        outv[j]   = (short)f2bf(fa[j]);
        outv[4+j] = (short)f2bf(fb[j]);
      }
      *(v8s*)(Ah + ga) = outv;
    }
  }
}

// ---- final: Ah via global_load_lds, GEMM pi-matched Wo, +bias +x; 2 blk/CU ----
__global__ __launch_bounds__(512,4)
void final2_kernel(const float* __restrict__ x, const unsigned short* __restrict__ wsWo,
                   const float* __restrict__ bo, const unsigned short* __restrict__ Ah,
                   float* __restrict__ out)
{
  __shared__ __align__(16) char smem[81920];
  unsigned short* asl = (unsigned short*)smem;            // [128 pos][256 c] swz
  unsigned short* wol = (unsigned short*)(smem + 65536);  // [32 o][256 c] swz

  const int tid = threadIdx.x;
  const int b = blockIdx.x >> 7, pt = blockIdx.x & 127;
  {
    const char* ab = (const char*)(Ah + ((size_t)b*16384 + (size_t)pt*128)*256);
    for (int i=0;i<8;++i)
      gload_lds16(ab + (i*512+tid)*16, (char*)asl + (i*512+tid)*16);
  }
  const int lane = tid & 63, wv = tid >> 6;
  const int lr = lane & 15, lk = lane >> 4;
  const f32x4 zero4 = {0.f,0.f,0.f,0.f};

  for (int oc = 0; oc < 8; ++oc){
    {
      const char* wb = (const char*)wsWo + oc*16384;
      for (int rIt=0;rIt<2;++rIt)
        gload_lds16(wb + (rIt*512+tid)*16, (char*)wol + (rIt*512+tid)*16);
    }
    const float b0v = bo[oc*32 + lr], b1v = bo[oc*32 + 16 + lr];
    __syncthreads();

    f32x4 a0 = zero4, a1 = zero4;
    #pragma unroll
    for (int ks = 0; ks < 8; ++ks){
      int c0 = ks*32 + lk*8;
      v8s av = *(const v8s*)(asl + xs_idx(wv*16 + lr, c0));
      v8s b0 = *(const v8s*)(wol + wl_idx(     lr, c0));
      v8s b1 = *(const v8s*)(wol + wl_idx(16 + lr, c0));
      a0 = mfma16(av, b0, a0);
      a1 = mfma16(av, b1, a1);
    }
    {
      int base0 = ((b*C_ + oc*32 + lr)*HH)*WW + pt*128 + wv*16 + lk*4;
      f32x4 xv0 = *(const f32x4*)(x + base0);
      f32x4 xv1 = *(const f32x4*)(x + base0 + 16*HH*WW);
      f32x4 r0 = a0 + xv0 + b0v;
      f32x4 r1 = a1 + xv1 + b1v;
      *(f32x4*)(out + base0) = r0;
      *(f32x4*)(out + base0 + 16*HH*WW) = r1;
    }
    __syncthreads();
  }
}

extern "C" void kernel_launch(void* const* d_in, const int* in_sizes, int n_in,
                              void* d_out, int out_size, void* d_ws, size_t ws_size,
                              hipStream_t stream) {
  const float* x  = (const float*)d_in[0];
  const float* Wq = (const float*)d_in[1];
  const float* bq = (const float*)d_in[2];
  const float* Wk = (const float*)d_in[3];
  const float* bk = (const float*)d_in[4];
  const float* Wv = (const float*)d_in[5];
  const float* bv = (const float*)d_in[6];
  const float* Wo = (const float*)d_in[7];
  const float* bo = (const float*)d_in[8];
  float* out = (float*)d_out;

  unsigned short* wsW  = (unsigned short*)d_ws;
  unsigned short* wsWo = (unsigned short*)((char*)d_ws + 393216);
  unsigned short* Qw   = (unsigned short*)((char*)d_ws + 524288);
  unsigned short* Kw   = Qw + 33554432;
  unsigned short* Vw   = Kw + 33554432;
  unsigned short* Ah   = (unsigned short*)((char*)d_ws + WS_OFF_AH);

  prep_w_kernel<<<dim3(128),  dim3(512), 0, stream>>>(Wq, Wk, Wv, Wo, wsW, wsWo);
  proj7_kernel <<<dim3(1024), dim3(512), 0, stream>>>(x, bq, bk, bv, wsW, Qw, Kw, Vw);
  attn2_kernel<0><<<dim3(8192), dim3(512), 0, stream>>>(Qw, Kw, Vw, Ah);
  attn2_kernel<1><<<dim3(8192), dim3(512), 0, stream>>>(Qw, Kw, Vw, Ah);
  final2_kernel<<<dim3(1024), dim3(512), 0, stream>>>(x, wsWo, bo, Ah, out);
}

// Round 12
// 266.376 us; speedup vs baseline: 1.4720x; 1.0039x over previous
//
#include <hip/hip_runtime.h>

#define B_ 8
#define C_ 256
#define HH 128
#define WW 128
#define HEADS_ 8
#define SCALE 0.17677669529663687f   // 32^-0.5

typedef short v8s __attribute__((ext_vector_type(8)));
typedef float f32x4 __attribute__((ext_vector_type(4)));

__device__ __forceinline__ unsigned short f2bf(float f){
  unsigned int u = __float_as_uint(f);
  u += 0x7FFFu + ((u>>16)&1u);
  return (unsigned short)(u>>16);
}
__device__ __forceinline__ float bf2f(unsigned short s){ return __uint_as_float(((unsigned int)s)<<16); }
__device__ __forceinline__ f32x4 mfma16(v8s a, v8s b, f32x4 c){
  return __builtin_amdgcn_mfma_f32_16x16x32_bf16(a,b,c,0,0,0);
}
__device__ __forceinline__ int xs_idx(int s,int c){ return s*256 + ((((c>>3)^(s&31))&31)<<3) + (c&7); }
__device__ __forceinline__ int wl_idx(int dm,int c){ return dm*256 + ((((c>>3)^(dm&31))&31)<<3) + (c&7); }
__device__ __forceinline__ void gload_lds16(const void* g, void* l){
  __builtin_amdgcn_global_load_lds((const __attribute__((address_space(1))) unsigned int*)g,
                                   (__attribute__((address_space(3))) unsigned int*)l, 16, 0, 0);
}

// ws layout (bytes):
//   [0, 393216)            wsW : 8 heads x (96x256) bf16 pre-swizzled
//   [393216, 524288)       wsWo: 8 oc x (32x256) bf16 pre-swizzled, c-dim pi-permuted
//   [524288, +3*67108864)  Qw, Kw, Vw : [b][head][16384 pos][32 d(pi)] bf16
//   [201850880, +67108864) Ah  : [b][16384 pos][256 c(pi)] bf16, chunk-swizzled
// pi-permutation within each head's 32 d: slot i holds true d = (i&1)*16 + (i>>1).
#define WS_OFF_AH 201850880ULL

__global__ __launch_bounds__(512,4)
void prep_w_kernel(const float* __restrict__ Wq, const float* __restrict__ Wk,
                   const float* __restrict__ Wv, const float* __restrict__ Wo,
                   unsigned short* __restrict__ wsW, unsigned short* __restrict__ wsWo){
  const int bid = blockIdx.x, t = threadIdx.x;
  if (bid < 96){
    int h = bid/12, seg = bid%12;
    int dm = seg*8 + (t>>6), c = (t&63)*4;
    const float* Wm = dm<32 ? Wq : (dm<64 ? Wk : Wv);
    const float4 w4 = *(const float4*)&Wm[(h*32 + (dm&31))*C_ + c];
    ushort4 pk = { f2bf(w4.x), f2bf(w4.y), f2bf(w4.z), f2bf(w4.w) };
    *(ushort4*)(wsW + h*24576 + wl_idx(dm, c)) = pk;
  } else {
    int q = bid - 96;
    int oc = q>>2, seg = q&3;
    int o = seg*8 + (t>>6), cs = (t&63)*4;   // cs = contraction slot base
    float w[4];
    #pragma unroll
    for (int j=0;j<4;++j){
      int s = cs + j;
      int ctrue = (s & ~31) | ((s&1)<<4) | ((s&31)>>1);
      w[j] = Wo[(oc*32+o)*C_ + ctrue];
    }
    ushort4 pk = { f2bf(w[0]), f2bf(w[1]), f2bf(w[2]), f2bf(w[3]) };
    *(ushort4*)(wsWo + oc*8192 + wl_idx(o, cs)) = pk;
  }
}

// ---- proj8: proj7 + proj4-style overlap: writeout(h-1) || MFMA(h); 2 barriers/head ----
// Race safety (validated by proj4's passing run): barrier B's per-thread lgkmcnt(0)
// retires writeout rp-reads before repack rewrites rp, and wl-reads before prefetch
// overwrites wl. Store-ack drains at barrier B, after MFMA.
__global__ __launch_bounds__(512,4)
void proj8_kernel(const float* __restrict__ x,
                  const float* __restrict__ bq, const float* __restrict__ bk,
                  const float* __restrict__ bv,
                  const unsigned short* __restrict__ wsW,
                  unsigned short* __restrict__ Qw, unsigned short* __restrict__ Kw,
                  unsigned short* __restrict__ Vw){
  __shared__ __align__(16) char smem[76800];
  unsigned short* xs = (unsigned short*)smem;            // phase 0 only (64K)
  unsigned short* wl = (unsigned short*)smem;            // [96][256] swz (48K)
  unsigned short* rp = (unsigned short*)(smem + 49152);  // [128][104] (26.6K)

  const int tid = threadIdx.x;
  const int b = blockIdx.x >> 7, pt = blockIdx.x & 127;
  const size_t pos0 = (size_t)pt * 128;

  {  // stage x tile -> xs (bf16 swizzled [pos][c]); coalesced float4 along pos
    const int cq = (tid>>5)*2, pl = (tid&31)*4;
    #pragma unroll
    for (int j=0;j<8;++j){
      int c0 = j*32 + cq;
      const float4 a0 = *(const float4*)&x[((size_t)(b*C_ + c0  ))*16384 + pos0 + pl];
      const float4 a1 = *(const float4*)&x[((size_t)(b*C_ + c0+1))*16384 + pos0 + pl];
      unsigned int p0 = (unsigned)f2bf(a0.x) | ((unsigned)f2bf(a1.x)<<16);
      unsigned int p1 = (unsigned)f2bf(a0.y) | ((unsigned)f2bf(a1.y)<<16);
      unsigned int p2 = (unsigned)f2bf(a0.z) | ((unsigned)f2bf(a1.z)<<16);
      unsigned int p3 = (unsigned)f2bf(a0.w) | ((unsigned)f2bf(a1.w)<<16);
      *(unsigned int*)&xs[xs_idx(pl+0, c0)] = p0;
      *(unsigned int*)&xs[xs_idx(pl+1, c0)] = p1;
      *(unsigned int*)&xs[xs_idx(pl+2, c0)] = p2;
      *(unsigned int*)&xs[xs_idx(pl+3, c0)] = p3;
    }
  }
  __syncthreads();                     // xs visible

  const int lane = tid&63, wv = tid>>6, lr = lane&15, lk = lane>>4;
  v8s areg[8];
  #pragma unroll
  for (int ks=0;ks<8;++ks) areg[ks] = *(const v8s*)(xs + xs_idx(wv*16+lr, ks*32+lk*8));
  __syncthreads();                     // xs consumed; region becomes wl

  {  // issue wl(head 0)
    const char* wb = (const char*)wsW;
    for (int rIt=0;rIt<6;++rIt)
      gload_lds16(wb + (rIt*512+tid)*16, (char*)wl + (rIt*512+tid)*16);
  }

  const f32x4 zero4 = {0.f,0.f,0.f,0.f};
  const int wp = tid>>2, wch = tid&3;  // writeout mapping (block-wide)

  for (int h=0; h<HEADS_; ++h){
    __syncthreads();                   // A: wl(h) ready (drains prefetch); rp(h-1) visible
    // ---- writeout(h-1): issues here, overlaps MFMA below ----
    if (h > 0){
      v8s qd = *(const v8s*)&rp[wp*104 +      wch*8];
      v8s kd = *(const v8s*)&rp[wp*104 + 32 + wch*8];
      v8s vd = *(const v8s*)&rp[wp*104 + 64 + wch*8];
      size_t og = ((size_t)(b*HEADS_+(h-1))*16384 + pos0 + wp)*32 + wch*8;
      *(v8s*)(Qw + og) = qd;
      *(v8s*)(Kw + og) = kd;
      *(v8s*)(Vw + og) = vd;
    }
    // ---- projection MFMA ----
    f32x4 acc[6];
    #pragma unroll
    for (int n=0;n<6;++n) acc[n]=zero4;
    #pragma unroll
    for (int ks=0;ks<8;++ks){
      int c0 = ks*32 + lk*8;
      #pragma unroll
      for (int n=0;n<6;++n){
        v8s bb = *(const v8s*)(wl + wl_idx(n*16+lr, c0));
        acc[n] = mfma16(areg[ks], bb, acc[n]);
      }
    }
    __syncthreads();                   // B: wl reads + rp writeout-reads done
    if (h < HEADS_-1){                 // prefetch wl(h+1)
      const char* wb = (const char*)wsW + (h+1)*49152;
      for (int rIt=0;rIt<6;++rIt)
        gload_lds16(wb + (rIt*512+tid)*16, (char*)wl + (rIt*512+tid)*16);
    }
    // ---- repack acc(h) -> rp, pi-packed (12 b32 writes) ----
    #pragma unroll
    for (int g=0; g<3; ++g){
      const float* bm = g==0 ? bq : (g==1 ? bk : bv);
      float bv0 = bm[h*32 + lr];
      float bv1 = bm[h*32 + 16 + lr];
      #pragma unroll
      for (int rr=0;rr<4;++rr){
        int pos = wv*16 + lk*4 + rr;
        float v0 = acc[2*g  ][rr] + bv0;
        float v1 = acc[2*g+1][rr] + bv1;
        if (g==0){ v0 *= SCALE; v1 *= SCALE; }
        unsigned int pkv = (unsigned)f2bf(v0) | ((unsigned)f2bf(v1)<<16);
        *(unsigned int*)&rp[pos*104 + g*32 + lr*2] = pkv;
      }
    }
  }
  __syncthreads();                     // rp(7) visible
  {
    v8s qd = *(const v8s*)&rp[wp*104 +      wch*8];
    v8s kd = *(const v8s*)&rp[wp*104 + 32 + wch*8];
    v8s vd = *(const v8s*)&rp[wp*104 + 64 + wch*8];
    size_t og = ((size_t)(b*HEADS_+7)*16384 + pos0 + wp)*32 + wch*8;
    *(v8s*)(Qw + og) = qd;
    *(v8s*)(Kw + og) = kd;
    *(v8s*)(Vw + og) = vd;
  }
}

// ---- attention (R4-proven, d-order opaque): swapped QK^T, in-reg PV, Ah out ----
template<int VERT>
__global__ __launch_bounds__(512,6)
void attn2_kernel(const unsigned short* __restrict__ Qw, const unsigned short* __restrict__ Kw,
                  const unsigned short* __restrict__ Vw, unsigned short* __restrict__ Ah){
  __shared__ __align__(16) char smem[37376];
  unsigned short* kl = (unsigned short*)smem;            // [128 key][40 d]
  unsigned short* Vt = (unsigned short*)(smem + 10240);  // [32 d][136 slot]
  float*          ob = (float*)(smem + 18944);           // [128 s][36 d]

  const int tid = threadIdx.x;
  int b, head, fix;
  if (VERT){ int xcd = blockIdx.x&7, rest = blockIdx.x>>3;
             fix = xcd*16 + (rest&15); head = (rest>>4)&7; b = rest>>7; }
  else     { head = blockIdx.x&7; fix = (blockIdx.x>>3)&127; b = blockIdx.x>>10; }
  const size_t tb = (size_t)(b*HEADS_+head)*16384*32;
  const int lane = tid&63, wvq = tid>>6, lr = lane&15, lk = lane>>4;
  const f32x4 zero4 = {0.f,0.f,0.f,0.f};

  {
    int pl = tid>>2, ch = tid&3;
    size_t g = tb + (VERT ? ((size_t)pl*128 + fix) : ((size_t)fix*128 + pl))*32 + ch*8;
    v8s kv = *(const v8s*)(Kw + g);
    v8s vv = *(const v8s*)(Vw + g);
    *(v8s*)&kl[pl*40 + ch*8] = kv;
    int slot = (pl & ~31) | (((pl>>2)&3)<<3) | (((pl>>4)&1)<<2) | (pl&3);
    #pragma unroll
    for (int j=0;j<8;++j) Vt[(ch*8+j)*136 + slot] = (unsigned short)vv[j];
  }
  const int posq = VERT ? (wvq*16+lr)*128 + fix : fix*128 + (wvq*16+lr);
  v8s qa = *(const v8s*)(Qw + tb + (size_t)posq*32 + lk*8);
  __syncthreads();

  f32x4 sc[8];
  #pragma unroll
  for (int kt=0;kt<8;++kt){
    v8s kb = *(const v8s*)&kl[(kt*16+lr)*40 + lk*8];
    sc[kt] = mfma16(kb, qa, zero4);
  }
  float mx = sc[0][0];
  #pragma unroll
  for (int kt=0;kt<8;++kt){
    #pragma unroll
    for (int rr=0;rr<4;++rr) mx = fmaxf(mx, sc[kt][rr]);
  }
  mx = fmaxf(mx, __shfl_xor(mx, 16));
  mx = fmaxf(mx, __shfl_xor(mx, 32));
  float sm = 0.f;
  #pragma unroll
  for (int kt=0;kt<8;++kt){
    #pragma unroll
    for (int rr=0;rr<4;++rr){ float p = __expf(sc[kt][rr]-mx); sc[kt][rr]=p; sm += p; }
  }
  sm += __shfl_xor(sm, 16);
  sm += __shfl_xor(sm, 32);
  const float rn = 1.f/sm;
  unsigned int pk[16];
  #pragma unroll
  for (int kt=0;kt<8;++kt){
    pk[kt*2  ] = (unsigned)f2bf(sc[kt][0]*rn) | ((unsigned)f2bf(sc[kt][1]*rn)<<16);
    pk[kt*2+1] = (unsigned)f2bf(sc[kt][2]*rn) | ((unsigned)f2bf(sc[kt][3]*rn)<<16);
  }
  f32x4 o0 = zero4, o1 = zero4;
  #pragma unroll
  for (int ks=0;ks<4;++ks){
    union { unsigned int u[4]; v8s v; } pa;
    pa.u[0]=pk[4*ks]; pa.u[1]=pk[4*ks+1]; pa.u[2]=pk[4*ks+2]; pa.u[3]=pk[4*ks+3];
    v8s v0 = *(const v8s*)&Vt[(     lr)*136 + ks*32 + lk*8];
    v8s v1 = *(const v8s*)&Vt[(16 + lr)*136 + ks*32 + lk*8];
    o0 = mfma16(pa.v, v0, o0);
    o1 = mfma16(pa.v, v1, o1);
  }
  #pragma unroll
  for (int rr=0;rr<4;++rr){
    int s = wvq*16 + lk*4 + rr;
    ob[s*36 + lr     ] = o0[rr];
    ob[s*36 + 16 + lr] = o1[rr];
  }
  {
    int row = wvq*16 + (lane>>2), jj = lane&3;
    f32x4 fa = *(const f32x4*)&ob[row*36 + jj*8];
    f32x4 fb = *(const f32x4*)&ob[row*36 + jj*8 + 4];
    int pos = VERT ? row*128 + fix : fix*128 + row;
    size_t ga = ((size_t)b*16384 + pos)*256 + (size_t)(((head*4+jj)^(pos&31))<<3);
    if (VERT){
      v8s prev = *(const v8s*)(Ah + ga);
      v8s outv;
      #pragma unroll
      for (int j=0;j<4;++j){
        outv[j]   = (short)f2bf(bf2f((unsigned short)prev[j])   + fa[j]);
        outv[4+j] = (short)f2bf(bf2f((unsigned short)prev[4+j]) + fb[j]);
      }
      *(v8s*)(Ah + ga) = outv;
    } else {
      v8s outv;
      #pragma unroll
      for (int j=0;j<4;++j){
        outv[j]   = (short)f2bf(fa[j]);
        outv[4+j] = (short)f2bf(fb[j]);
      }
      *(v8s*)(Ah + ga) = outv;
    }
  }
}

// ---- final: Ah via global_load_lds, GEMM pi-matched Wo, +bias +x; 2 blk/CU ----
__global__ __launch_bounds__(512,4)
void final2_kernel(const float* __restrict__ x, const unsigned short* __restrict__ wsWo,
                   const float* __restrict__ bo, const unsigned short* __restrict__ Ah,
                   float* __restrict__ out)
{
  __shared__ __align__(16) char smem[81920];
  unsigned short* asl = (unsigned short*)smem;            // [128 pos][256 c] swz
  unsigned short* wol = (unsigned short*)(smem + 65536);  // [32 o][256 c] swz

  const int tid = threadIdx.x;
  const int b = blockIdx.x >> 7, pt = blockIdx.x & 127;
  {
    const char* ab = (const char*)(Ah + ((size_t)b*16384 + (size_t)pt*128)*256);
    for (int i=0;i<8;++i)
      gload_lds16(ab + (i*512+tid)*16, (char*)asl + (i*512+tid)*16);
  }
  const int lane = tid & 63, wv = tid >> 6;
  const int lr = lane & 15, lk = lane >> 4;
  const f32x4 zero4 = {0.f,0.f,0.f,0.f};

  for (int oc = 0; oc < 8; ++oc){
    {
      const char* wb = (const char*)wsWo + oc*16384;
      for (int rIt=0;rIt<2;++rIt)
        gload_lds16(wb + (rIt*512+tid)*16, (char*)wol + (rIt*512+tid)*16);
    }
    const float b0v = bo[oc*32 + lr], b1v = bo[oc*32 + 16 + lr];
    __syncthreads();

    f32x4 a0 = zero4, a1 = zero4;
    #pragma unroll
    for (int ks = 0; ks < 8; ++ks){
      int c0 = ks*32 + lk*8;
      v8s av = *(const v8s*)(asl + xs_idx(wv*16 + lr, c0));
      v8s b0 = *(const v8s*)(wol + wl_idx(     lr, c0));
      v8s b1 = *(const v8s*)(wol + wl_idx(16 + lr, c0));
      a0 = mfma16(av, b0, a0);
      a1 = mfma16(av, b1, a1);
    }
    {
      int base0 = ((b*C_ + oc*32 + lr)*HH)*WW + pt*128 + wv*16 + lk*4;
      f32x4 xv0 = *(const f32x4*)(x + base0);
      f32x4 xv1 = *(const f32x4*)(x + base0 + 16*HH*WW);
      f32x4 r0 = a0 + xv0 + b0v;
      f32x4 r1 = a1 + xv1 + b1v;
      *(f32x4*)(out + base0) = r0;
      *(f32x4*)(out + base0 + 16*HH*WW) = r1;
    }
    __syncthreads();
  }
}

extern "C" void kernel_launch(void* const* d_in, const int* in_sizes, int n_in,
                              void* d_out, int out_size, void* d_ws, size_t ws_size,
                              hipStream_t stream) {
  const float* x  = (const float*)d_in[0];
  const float* Wq = (const float*)d_in[1];
  const float* bq = (const float*)d_in[2];
  const float* Wk = (const float*)d_in[3];
  const float* bk = (const float*)d_in[4];
  const float* Wv = (const float*)d_in[5];
  const float* bv = (const float*)d_in[6];
  const float* Wo = (const float*)d_in[7];
  const float* bo = (const float*)d_in[8];
  float* out = (float*)d_out;

  unsigned short* wsW  = (unsigned short*)d_ws;
  unsigned short* wsWo = (unsigned short*)((char*)d_ws + 393216);
  unsigned short* Qw   = (unsigned short*)((char*)d_ws + 524288);
  unsigned short* Kw   = Qw + 33554432;
  unsigned short* Vw   = Kw + 33554432;
  unsigned short* Ah   = (unsigned short*)((char*)d_ws + WS_OFF_AH);

  prep_w_kernel<<<dim3(128),  dim3(512), 0, stream>>>(Wq, Wk, Wv, Wo, wsW, wsWo);
  proj8_kernel <<<dim3(1024), dim3(512), 0, stream>>>(x, bq, bk, bv, wsW, Qw, Kw, Vw);
  attn2_kernel<0><<<dim3(8192), dim3(512), 0, stream>>>(Qw, Kw, Vw, Ah);
  attn2_kernel<1><<<dim3(8192), dim3(512), 0, stream>>>(Qw, Kw, Vw, Ah);
  final2_kernel<<<dim3(1024), dim3(512), 0, stream>>>(x, wsWo, bo, Ah, out);
}